// Round 2
// baseline (978.970 us; speedup 1.0000x reference)
//
#include <hip/hip_runtime.h>

typedef unsigned short u16;
typedef __bf16 bf16x8 __attribute__((ext_vector_type(8)));
typedef float f32x4 __attribute__((ext_vector_type(4)));

#define S_LEN 2048
#define D_DIM 2048
#define NH 16
#define DH 128
#define HID 8192

__device__ __forceinline__ u16 f2bf(float f) {
  unsigned int u = __float_as_uint(f);
  u += 0x7fff + ((u >> 16) & 1);   // round-to-nearest-even
  return (u16)(u >> 16);
}

// async global->LDS, 16 bytes per lane (global_load_lds_dwordx4)
__device__ __forceinline__ void gld16(const u16* g, u16* l) {
  __builtin_amdgcn_global_load_lds(
      (const __attribute__((address_space(1))) unsigned int*)g,
      (__attribute__((address_space(3))) unsigned int*)l, 16, 0, 0);
}

// ---------------------------------------------------------------------------
// Transpose-convert: in [R][C] fp32 -> out [C][R] bf16, batched over blockIdx.z
// ---------------------------------------------------------------------------
__global__ __launch_bounds__(256) void tconv_f2b(const float* __restrict__ in,
                                                 u16* __restrict__ out, int R, int C) {
  __shared__ float tile[32][33];
  size_t boff = (size_t)blockIdx.z * R * C;
  in += boff; out += boff;
  int c0 = blockIdx.x * 32, r0 = blockIdx.y * 32;
  int tx = threadIdx.x, ty = threadIdx.y;
#pragma unroll
  for (int i = 0; i < 32; i += 8) tile[ty + i][tx] = in[(size_t)(r0 + ty + i) * C + c0 + tx];
  __syncthreads();
#pragma unroll
  for (int i = 0; i < 32; i += 8) out[(size_t)(c0 + ty + i) * R + r0 + tx] = f2bf(tile[tx][ty + i]);
}

// bf16 -> bf16 transpose (for V -> V^T)
__global__ __launch_bounds__(256) void tconv_b2b(const u16* __restrict__ in,
                                                 u16* __restrict__ out, int R, int C) {
  __shared__ u16 tile[32][34];
  size_t boff = (size_t)blockIdx.z * R * C;
  in += boff; out += boff;
  int c0 = blockIdx.x * 32, r0 = blockIdx.y * 32;
  int tx = threadIdx.x, ty = threadIdx.y;
#pragma unroll
  for (int i = 0; i < 32; i += 8) tile[ty + i][tx] = in[(size_t)(r0 + ty + i) * C + c0 + tx];
  __syncthreads();
#pragma unroll
  for (int i = 0; i < 32; i += 8) out[(size_t)(c0 + ty + i) * R + r0 + tx] = tile[tx][ty + i];
}

// ---------------------------------------------------------------------------
// RMSNorm: per-row (D=2048), writes fp32 (optional) and bf16
// ---------------------------------------------------------------------------
__global__ __launch_bounds__(256) void rmsnorm_kernel(const float* __restrict__ x,
                                                      const float* __restrict__ g,
                                                      float* __restrict__ xf,
                                                      u16* __restrict__ xb) {
  int row = blockIdx.x;
  int t = threadIdx.x;
  const float4* xr = (const float4*)(x + (size_t)row * D_DIM);
  float4 v0 = xr[t];
  float4 v1 = xr[t + 256];
  float ss = v0.x * v0.x + v0.y * v0.y + v0.z * v0.z + v0.w * v0.w +
             v1.x * v1.x + v1.y * v1.y + v1.z * v1.z + v1.w * v1.w;
#pragma unroll
  for (int o = 1; o < 64; o <<= 1) ss += __shfl_xor(ss, o, 64);
  __shared__ float wss[4];
  if ((t & 63) == 0) wss[t >> 6] = ss;
  __syncthreads();
  float tot = wss[0] + wss[1] + wss[2] + wss[3];
  float rs = rsqrtf(tot * (1.0f / D_DIM) + 1e-6f);
  const float4* gr = (const float4*)g;
  float4 g0 = gr[t], g1 = gr[t + 256];
  float4 o0, o1;
  o0.x = v0.x * rs * g0.x; o0.y = v0.y * rs * g0.y; o0.z = v0.z * rs * g0.z; o0.w = v0.w * rs * g0.w;
  o1.x = v1.x * rs * g1.x; o1.y = v1.y * rs * g1.y; o1.z = v1.z * rs * g1.z; o1.w = v1.w * rs * g1.w;
  if (xf) {
    float4* xfr = (float4*)(xf + (size_t)row * D_DIM);
    xfr[t] = o0; xfr[t + 256] = o1;
  }
  ushort4 b0, b1;
  b0.x = f2bf(o0.x); b0.y = f2bf(o0.y); b0.z = f2bf(o0.z); b0.w = f2bf(o0.w);
  b1.x = f2bf(o1.x); b1.y = f2bf(o1.y); b1.z = f2bf(o1.z); b1.w = f2bf(o1.w);
  ushort4* xbr = (ushort4*)(xb + (size_t)row * D_DIM);
  xbr[t] = b0; xbr[t + 256] = b1;
}

// ---------------------------------------------------------------------------
// lambda[h] = exp(lq1.lk1) - exp(lq2.lk2) + 0.8
// ---------------------------------------------------------------------------
__global__ __launch_bounds__(256) void lam_kernel(const float* __restrict__ lq1,
                                                  const float* __restrict__ lk1,
                                                  const float* __restrict__ lq2,
                                                  const float* __restrict__ lk2,
                                                  float* __restrict__ lamw) {
  int t = threadIdx.x;
  int h = t >> 4, i = (t & 15) << 3;
  float d1 = 0.f, d2 = 0.f;
#pragma unroll
  for (int j = 0; j < 8; j++) {
    d1 += lq1[h * DH + i + j] * lk1[h * DH + i + j];
    d2 += lq2[h * DH + i + j] * lk2[h * DH + i + j];
  }
#pragma unroll
  for (int o = 1; o < 16; o <<= 1) { d1 += __shfl_xor(d1, o, 64); d2 += __shfl_xor(d2, o, 64); }
  if ((t & 15) == 0) lamw[h] = __expf(d1) - __expf(d2) + 0.8f;
}

// ---------------------------------------------------------------------------
// gemm8_proj: deep-pipelined flattened projection GEMM (T3+T4+T2+T5).
// C[M=2048, N=10240] = A[M,K=2048] @ Wcat[N,K]^T, all bf16.
// BM=256, BN=128, BK=64, 512 threads (8 waves, 2M x 4N), 3-buffer LDS ring.
// Counted vmcnt(6) at each tile boundary -- next-next tile's 6 loads stay in
// flight across every barrier; vmcnt never drains to 0 in the main loop.
// LDS XOR-swizzle byte^=(row&7)<<4 on A and B tiles (rule #21: linear
// global_load_lds dest + inverse-swizzled global SOURCE + swizzled ds_read).
// Epilogue permutes columns into the 5 contiguous proj tensors:
//   col n -> tensor-head chunk (n>>7), inner dh (n&127):
//   out[(n>>7)*S*128 + row*128 + (n&127)]
// ---------------------------------------------------------------------------
__global__ __launch_bounds__(512) void gemm8_proj(const u16* __restrict__ A,
                                                  const u16* __restrict__ Bt,
                                                  u16* __restrict__ Out,
                                                  int M, int N, int K) {
  constexpr int BM = 256, BN = 128, BK = 64, NBUF = 3;
  __shared__ __align__(16) u16 As[NBUF][BM * BK];  // 3 x 32 KiB
  __shared__ __align__(16) u16 Bs[NBUF][BN * BK];  // 3 x 16 KiB
  const int t = threadIdx.x;            // 0..511
  const int lane = t & 63;
  const int wid = t >> 6;               // 8 waves
  const int wm = (wid >> 2) * 128;      // 0,128
  const int wn = (wid & 3) * 32;        // 0,32,64,96
  const int fr = lane & 15, fq = lane >> 4;
  const int m0 = blockIdx.y * BM, n0 = blockIdx.x * BN;

  f32x4 acc[8][2] = {};

  // staging: issue slot s covers LDS bytes [s*8192, (s+1)*8192), thread t owns
  // bytes [t*16, t*16+16) of the slot (linear dest = wave base + lane*16).
  // logical (row,colbyte) of linear byte B: row = B>>7, cb = (B&127) ^ ((row&7)<<4)
  const int sro = t >> 3;                                // row within slot (0..63)
  const int scol = ((((t & 7) ^ (sro & 7)) << 4) >> 1);  // pre-swizzled elem col
  const u16* aSrc = A + (size_t)(m0 + sro) * K + scol;
  const u16* bSrc = Bt + (size_t)(n0 + sro) * K + scol;

  const int NT = K >> 6;  // 32 K-tiles

#define STAGE_A(buf, k0, s) gld16(aSrc + (size_t)((s)*64) * K + (k0), &As[buf][(s)*4096 + t * 8])
#define STAGE_B(buf, k0, s) gld16(bSrc + (size_t)((s)*64) * K + (k0), &Bs[buf][(s)*4096 + t * 8])

  // prologue: stage tiles 0 and 1 (6 loads each), wait tile 0 only (vmcnt 6)
  STAGE_A(0, 0, 0); STAGE_A(0, 0, 1); STAGE_A(0, 0, 2); STAGE_A(0, 0, 3);
  STAGE_B(0, 0, 0); STAGE_B(0, 0, 1);
  STAGE_A(1, BK, 0); STAGE_A(1, BK, 1); STAGE_A(1, BK, 2); STAGE_A(1, BK, 3);
  STAGE_B(1, BK, 0); STAGE_B(1, BK, 1);
  asm volatile("s_waitcnt vmcnt(6)" ::: "memory");
  __builtin_amdgcn_s_barrier();

  const int swz = (fr & 7) << 4;  // read-side column-byte XOR

  for (int tk = 0; tk < NT; ++tk) {
    const int r = tk % 3;
    const int pf = tk + 2;
    const int pbuf = pf % 3;        // == (tk-1)%3: consumed last tile, free
    const bool doPf = pf < NT;
    const int k0pf = pf << 6;

    // B fragments for this tile (reused across both phases)
    bf16x8 bfrag[2][2];
#pragma unroll
    for (int j = 0; j < 2; ++j)
#pragma unroll
      for (int kk = 0; kk < 2; ++kk) {
        int row = wn + j * 16 + fr;
        int cb = (kk * 64 + fq * 16) ^ swz;
        bfrag[j][kk] = *(const bf16x8*)&Bs[r][row * 64 + (cb >> 1)];
      }

#pragma unroll
    for (int ph = 0; ph < 2; ++ph) {
      if (doPf) {
        if (ph == 0) { STAGE_A(pbuf, k0pf, 0); STAGE_A(pbuf, k0pf, 1); STAGE_B(pbuf, k0pf, 0); }
        else         { STAGE_A(pbuf, k0pf, 2); STAGE_A(pbuf, k0pf, 3); STAGE_B(pbuf, k0pf, 1); }
      }
      bf16x8 af[4][2];
#pragma unroll
      for (int i = 0; i < 4; ++i)
#pragma unroll
        for (int kk = 0; kk < 2; ++kk) {
          int row = wm + ph * 64 + i * 16 + fr;
          int cb = (kk * 64 + fq * 16) ^ swz;
          af[i][kk] = *(const bf16x8*)&As[r][row * 64 + (cb >> 1)];
        }
      __builtin_amdgcn_s_setprio(1);
#pragma unroll
      for (int i = 0; i < 4; ++i)
#pragma unroll
        for (int j = 0; j < 2; ++j) {
          acc[ph * 4 + i][j] =
              __builtin_amdgcn_mfma_f32_16x16x32_bf16(af[i][0], bfrag[j][0], acc[ph * 4 + i][j], 0, 0, 0);
          acc[ph * 4 + i][j] =
              __builtin_amdgcn_mfma_f32_16x16x32_bf16(af[i][1], bfrag[j][1], acc[ph * 4 + i][j], 0, 0, 0);
        }
      __builtin_amdgcn_s_setprio(0);
    }

    if (tk + 1 < NT) {
      // wait: tile tk+1 fully landed; tile tk+2's 6 loads may stay in flight
      if (doPf) asm volatile("s_waitcnt vmcnt(6)" ::: "memory");
      else      asm volatile("s_waitcnt vmcnt(0)" ::: "memory");
      __builtin_amdgcn_s_barrier();
    }
  }

#undef STAGE_A
#undef STAGE_B

  // epilogue: permuted store into [tensor*16+head][S][128]
  const size_t headBase = (size_t)(n0 >> 7) * ((size_t)S_LEN * 128);
#pragma unroll
  for (int i = 0; i < 8; ++i)
#pragma unroll
    for (int j = 0; j < 2; ++j) {
      int row0 = m0 + wm + i * 16 + (fq << 2);
      int colL = wn + j * 16 + fr;  // 0..127 within the head chunk
#pragma unroll
      for (int rr = 0; rr < 4; ++rr)
        Out[headBase + (size_t)(row0 + rr) * 128 + colL] = f2bf(acc[i][j][rr]);
    }
}

// ---------------------------------------------------------------------------
// m97-style GEMM, 2-phase double-buffered (no XCD swizzle -- round-1 showed it
// scrambles locality at this L3-fit size: FETCH 133->533 MB).
// C[M,N] = A[M,K] @ Bt[N,K]^T, bf16 in, BM=128, BK=32.
// MODE 1: fp32 out = acc + res
// MODE 2: dual-B; bf16 out = silu(acc)*acc2
// ---------------------------------------------------------------------------
template <int MODE, int BN>
__global__ __launch_bounds__(256) void gemm_a(const u16* __restrict__ A,
                                              const u16* __restrict__ Bt,
                                              const u16* __restrict__ Bt2,
                                              void* __restrict__ Cout,
                                              const float* __restrict__ res,
                                              int M, int N, int K, long sBt, long sC) {
  constexpr int BM = 128, BK = 32;
  constexpr int JF = BN / 32;  // j-frags per wave
  __shared__ __align__(16) u16 As[2][BM * BK];
  __shared__ __align__(16) u16 Bs[2][BN * BK];
  __shared__ __align__(16) u16 Bs2[(MODE == 2) ? 2 : 1][(MODE == 2) ? BN * BK : 8];
  const int t = threadIdx.x;
  const int lane = t & 63, wid = t >> 6;
  const int wm = (wid >> 1) * 64, wn = (wid & 1) * (BN / 2);
  const int fr = lane & 15, fq = lane >> 4;
  const int m0 = blockIdx.y * BM, n0 = blockIdx.x * BN;
  const int bz = blockIdx.z;
  const u16* bt = Bt + (long)bz * sBt;
  f32x4 acc[4][JF] = {};
  f32x4 acc2[(MODE == 2) ? 4 : 1][(MODE == 2) ? JF : 1] = {};
  const int sr = t >> 2, sc = (t & 3) << 3;   // 16B-chunk row/col
  const u16* aG = A + (long)(m0 + sr) * K + sc;
  const u16* bG = bt + (long)(n0 + sr) * K + sc;
  const u16* b2G = (MODE == 2) ? (Bt2 + (long)(n0 + sr) * K + sc) : nullptr;

  auto stage = [&](int buf, int k0) {
    gld16(aG + k0, &As[buf][t * 8]);
    gld16(aG + (long)64 * K + k0, &As[buf][t * 8 + 64 * BK]);
    gld16(bG + k0, &Bs[buf][t * 8]);
    if (BN == 128) gld16(bG + (long)64 * K + k0, &Bs[buf][t * 8 + 64 * BK]);
    if (MODE == 2) {
      gld16(b2G + k0, &Bs2[buf][t * 8]);
      if (BN == 128) gld16(b2G + (long)64 * K + k0, &Bs2[buf][t * 8 + 64 * BK]);
    }
  };

  // prologue: stage tile 0, drain, barrier
  stage(0, 0);
  __syncthreads();

  int cur = 0;
  for (int k0 = 0; k0 < K; k0 += BK) {
    // issue next tile's async loads into the OTHER buffer first
    if (k0 + BK < K) stage(cur ^ 1, k0 + BK);

    bf16x8 af[4], bfr[JF];
#pragma unroll
    for (int i = 0; i < 4; i++) af[i] = *(const bf16x8*)&As[cur][(wm + i * 16 + fr) * BK + fq * 8];
#pragma unroll
    for (int j = 0; j < JF; j++) bfr[j] = *(const bf16x8*)&Bs[cur][(wn + j * 16 + fr) * BK + fq * 8];
    bf16x8 cf[(MODE == 2) ? JF : 1];
    if (MODE == 2) {
#pragma unroll
      for (int j = 0; j < JF; j++) cf[j] = *(const bf16x8*)&Bs2[cur][(wn + j * 16 + fr) * BK + fq * 8];
    }

    __builtin_amdgcn_s_setprio(1);
#pragma unroll
    for (int i = 0; i < 4; i++)
#pragma unroll
      for (int j = 0; j < JF; j++)
        acc[i][j] = __builtin_amdgcn_mfma_f32_16x16x32_bf16(af[i], bfr[j], acc[i][j], 0, 0, 0);
    if (MODE == 2) {
#pragma unroll
      for (int i = 0; i < 4; i++)
#pragma unroll
        for (int j = 0; j < JF; j++)
          acc2[i][j] = __builtin_amdgcn_mfma_f32_16x16x32_bf16(af[i], cf[j], acc2[i][j], 0, 0, 0);
    }
    __builtin_amdgcn_s_setprio(0);

    // single barrier per iter: drains this iter's async stage (vmcnt) and
    // all waves' ds_reads of buf[cur] before it gets overwritten next iter
    __syncthreads();
    cur ^= 1;
  }

#pragma unroll
  for (int i = 0; i < 4; i++)
#pragma unroll
    for (int j = 0; j < JF; j++) {
      int row0 = m0 + wm + i * 16 + (fq << 2);
      int col = n0 + wn + j * 16 + fr;
#pragma unroll
      for (int r = 0; r < 4; r++) {
        long idx = (long)(row0 + r) * N + col;
        float v = acc[i][j][r];
        if (MODE == 0) {
          ((u16*)Cout + (long)bz * sC)[idx] = f2bf(v);
        } else if (MODE == 1) {
          ((float*)Cout)[idx] = v + res[idx];
        } else {
          float g2 = acc2[i][j][r];
          float sg = v / (1.0f + __expf(-v));
          ((u16*)Cout)[idx] = f2bf(sg * g2);
        }
      }
    }
}

// ---------------------------------------------------------------------------
// Differential flash attention, static softmax (scores bounded; no max track).
// Denominator l comes free from the matrix pipe: P x ones-fragment MFMA.
// One block per (64-query tile, head).
// q1,q2,k1,k2: [H][S][DH] bf16;  vt: [H][DH][S] bf16;  o: [S][H*DH] bf16
// ---------------------------------------------------------------------------
#define LDK 136
#define LDV 40
#define LDP 40

__global__ __launch_bounds__(256) void flash_attn(const u16* __restrict__ q1g,
                                                  const u16* __restrict__ q2g,
                                                  const u16* __restrict__ k1g,
                                                  const u16* __restrict__ k2g,
                                                  const u16* __restrict__ vtg,
                                                  const float* __restrict__ lamw,
                                                  u16* __restrict__ og) {
  __shared__ __align__(16) u16 Ks1[32 * LDK];
  __shared__ __align__(16) u16 Ks2[32 * LDK];
  __shared__ __align__(16) u16 Vs[128 * LDV];
  __shared__ __align__(16) u16 Ps[4 * 2 * 16 * LDP];
  const float scale = 0.08838834764831845f;  // 1/sqrt(128)
  int h = blockIdx.y, qt = blockIdx.x;
  size_t hoff = (size_t)h * S_LEN * DH;
  const u16* q1 = q1g + hoff;
  const u16* q2 = q2g + hoff;
  const u16* k1 = k1g + hoff;
  const u16* k2 = k2g + hoff;
  const u16* vt = vtg + hoff;
  int t = threadIdx.x, wid = t >> 6, lane = t & 63;
  int fr = lane & 15, fq = lane >> 4;
  int qrow = qt * 64 + wid * 16 + fr;
  bf16x8 qf1[4], qf2[4];
#pragma unroll
  for (int ks = 0; ks < 4; ks++) {
    qf1[ks] = *(const bf16x8*)&q1[(size_t)qrow * DH + ks * 32 + fq * 8];
    qf2[ks] = *(const bf16x8*)&q2[(size_t)qrow * DH + ks * 32 + fq * 8];
  }
  bf16x8 ones;
#pragma unroll
  for (int i = 0; i < 8; i++) ones[i] = (__bf16)1.0f;

  f32x4 O1[8] = {};
  f32x4 O2[8] = {};
  f32x4 L1 = {};
  f32x4 L2 = {};
  int skr = t >> 3, skc = (t & 7) << 4;
  int svr = t >> 2, svc = (t & 3) << 3;
  u16* myP1 = &Ps[(wid * 2 + 0) * 16 * LDP];
  u16* myP2 = &Ps[(wid * 2 + 1) * 16 * LDP];

  for (int kt = 0; kt < S_LEN; kt += 32) {
    uint4 ka1 = *(const uint4*)&k1[(size_t)(kt + skr) * DH + skc];
    uint4 kb1 = *(const uint4*)&k1[(size_t)(kt + skr) * DH + skc + 8];
    uint4 ka2 = *(const uint4*)&k2[(size_t)(kt + skr) * DH + skc];
    uint4 kb2 = *(const uint4*)&k2[(size_t)(kt + skr) * DH + skc + 8];
    uint4 va = *(const uint4*)&vt[(size_t)svr * S_LEN + kt + svc];
    uint4 vb = *(const uint4*)&vt[(size_t)(svr + 64) * S_LEN + kt + svc];
    __syncthreads();
    *(uint4*)&Ks1[skr * LDK + skc] = ka1;
    *(uint4*)&Ks1[skr * LDK + skc + 8] = kb1;
    *(uint4*)&Ks2[skr * LDK + skc] = ka2;
    *(uint4*)&Ks2[skr * LDK + skc + 8] = kb2;
    *(uint4*)&Vs[svr * LDV + svc] = va;
    *(uint4*)&Vs[(svr + 64) * LDV + svc] = vb;
    __syncthreads();

    f32x4 s1[2] = {};
    f32x4 s2[2] = {};
#pragma unroll
    for (int nf = 0; nf < 2; nf++)
#pragma unroll
      for (int ks = 0; ks < 4; ks++) {
        bf16x8 b1v = *(const bf16x8*)&Ks1[(nf * 16 + fr) * LDK + ks * 32 + fq * 8];
        s1[nf] = __builtin_amdgcn_mfma_f32_16x16x32_bf16(qf1[ks], b1v, s1[nf], 0, 0, 0);
        bf16x8 b2v = *(const bf16x8*)&Ks2[(nf * 16 + fr) * LDK + ks * 32 + fq * 8];
        s2[nf] = __builtin_amdgcn_mfma_f32_16x16x32_bf16(qf2[ks], b2v, s2[nf], 0, 0, 0);
      }

    // static softmax: p = exp(s*scale); no max subtraction, no rescale
#pragma unroll
    for (int nf = 0; nf < 2; nf++)
#pragma unroll
      for (int r = 0; r < 4; r++) {
        myP1[(fq * 4 + r) * LDP + nf * 16 + fr] = f2bf(__expf(s1[nf][r] * scale));
        myP2[(fq * 4 + r) * LDP + nf * 16 + fr] = f2bf(__expf(s2[nf][r] * scale));
      }
    asm volatile("s_waitcnt lgkmcnt(0)" ::: "memory");
    bf16x8 pa1 = *(const bf16x8*)&myP1[fr * LDP + fq * 8];
    bf16x8 pa2 = *(const bf16x8*)&myP2[fr * LDP + fq * 8];
    L1 = __builtin_amdgcn_mfma_f32_16x16x32_bf16(pa1, ones, L1, 0, 0, 0);
    L2 = __builtin_amdgcn_mfma_f32_16x16x32_bf16(pa2, ones, L2, 0, 0, 0);
#pragma unroll
    for (int f = 0; f < 8; f++) {
      bf16x8 bv = *(const bf16x8*)&Vs[(f * 16 + fr) * LDV + fq * 8];
      O1[f] = __builtin_amdgcn_mfma_f32_16x16x32_bf16(pa1, bv, O1[f], 0, 0, 0);
      O2[f] = __builtin_amdgcn_mfma_f32_16x16x32_bf16(pa2, bv, O2[f], 0, 0, 0);
    }
  }

  float lam = lamw[h];
#pragma unroll
  for (int r = 0; r < 4; r++) {
    float i1 = 1.0f / L1[r], i2 = lam / L2[r];
#pragma unroll
    for (int f = 0; f < 8; f++) {
      float val = O1[f][r] * i1 - O2[f][r] * i2;
      og[(size_t)(qt * 64 + wid * 16 + fq * 4 + r) * (NH * DH) + h * DH + f * 16 + fr] =
          f2bf(val);
    }
  }
}

// ---------------------------------------------------------------------------
extern "C" void kernel_launch(void* const* d_in, const int* in_sizes, int n_in,
                              void* d_out, int out_size, void* d_ws, size_t ws_size,
                              hipStream_t stream) {
  const float* x = (const float*)d_in[0];
  const float* g = (const float*)d_in[1];
  const float* Wq1 = (const float*)d_in[2];
  const float* Wq2 = (const float*)d_in[3];
  const float* Wk1 = (const float*)d_in[4];
  const float* Wk2 = (const float*)d_in[5];
  const float* Wv = (const float*)d_in[6];
  const float* lq1 = (const float*)d_in[7];
  const float* lk1 = (const float*)d_in[8];
  const float* lq2 = (const float*)d_in[9];
  const float* lk2 = (const float*)d_in[10];
  const float* Wo = (const float*)d_in[11];
  const float* W1 = (const float*)d_in[12];
  const float* W2 = (const float*)d_in[13];
  const float* W3 = (const float*)d_in[14];

  char* ws = (char*)d_ws;
  size_t off = 0;
  auto alloc = [&](size_t b) {
    char* p = ws + off;
    off += (b + 255) & ~(size_t)255;
    return p;
  };
  const size_t PROJ_B = (size_t)NH * DH * D_DIM * 2;  // 8.39 MB, 256-aligned
  // 5 proj weights contiguous -> one flattened N=10240 GEMM reads them as Wcat
  u16* wq1t = (u16*)alloc(PROJ_B);
  u16* wq2t = (u16*)alloc(PROJ_B);
  u16* wk1t = (u16*)alloc(PROJ_B);
  u16* wk2t = (u16*)alloc(PROJ_B);
  u16* wvt = (u16*)alloc(PROJ_B);
  u16* wot = (u16*)alloc((size_t)D_DIM * NH * DH * 2);
  u16* w1t = (u16*)alloc((size_t)HID * D_DIM * 2);
  u16* w2t = (u16*)alloc((size_t)HID * D_DIM * 2);
  u16* w3t = (u16*)alloc((size_t)D_DIM * HID * 2);
  u16* xnb = (u16*)alloc((size_t)S_LEN * D_DIM * 2);
  float* xnf = (float*)alloc((size_t)S_LEN * D_DIM * 4);
  // 5 proj outputs contiguous (q1,q2,k1,k2,v)
  u16* q1b = (u16*)alloc(PROJ_B);
  u16* q2b = (u16*)alloc(PROJ_B);
  u16* k1b = (u16*)alloc(PROJ_B);
  u16* k2b = (u16*)alloc(PROJ_B);
  u16* vb = (u16*)alloc(PROJ_B);
  u16* vtb = (u16*)alloc(PROJ_B);
  float* lamw = (float*)alloc(NH * 4);
  u16* oa = (u16*)alloc((size_t)S_LEN * NH * DH * 2);
  float* hf = (float*)alloc((size_t)S_LEN * D_DIM * 4);
  u16* zb = (u16*)alloc((size_t)S_LEN * D_DIM * 2);
  u16* ffb = (u16*)alloc((size_t)S_LEN * HID * 2);
  if (off > ws_size) return;  // workspace too small: out stays zero -> loud failure

  dim3 tpb(32, 8);
  // weight transposes (fp32 -> bf16, [K,N] -> [N,K])
  tconv_f2b<<<dim3(DH / 32, D_DIM / 32, NH), tpb, 0, stream>>>(Wq1, wq1t, D_DIM, DH);
  tconv_f2b<<<dim3(DH / 32, D_DIM / 32, NH), tpb, 0, stream>>>(Wq2, wq2t, D_DIM, DH);
  tconv_f2b<<<dim3(DH / 32, D_DIM / 32, NH), tpb, 0, stream>>>(Wk1, wk1t, D_DIM, DH);
  tconv_f2b<<<dim3(DH / 32, D_DIM / 32, NH), tpb, 0, stream>>>(Wk2, wk2t, D_DIM, DH);
  tconv_f2b<<<dim3(DH / 32, D_DIM / 32, NH), tpb, 0, stream>>>(Wv, wvt, D_DIM, DH);
  tconv_f2b<<<dim3(D_DIM / 32, (NH * DH) / 32, 1), tpb, 0, stream>>>(Wo, wot, NH * DH, D_DIM);
  tconv_f2b<<<dim3(HID / 32, D_DIM / 32, 1), tpb, 0, stream>>>(W1, w1t, D_DIM, HID);
  tconv_f2b<<<dim3(HID / 32, D_DIM / 32, 1), tpb, 0, stream>>>(W2, w2t, D_DIM, HID);
  tconv_f2b<<<dim3(D_DIM / 32, HID / 32, 1), tpb, 0, stream>>>(W3, w3t, HID, D_DIM);

  rmsnorm_kernel<<<S_LEN, 256, 0, stream>>>(x, g, xnf, xnb);
  lam_kernel<<<1, 256, 0, stream>>>(lq1, lk1, lq2, lk2, lamw);

  // all 5 projections as ONE flattened GEMM: N = 5*16*128 = 10240
  gemm8_proj<<<dim3((5 * NH * DH) / 128, S_LEN / 256), 512, 0, stream>>>(
      xnb, wq1t, q1b, S_LEN, 5 * NH * DH, D_DIM);
  // V -> V^T per head
  tconv_b2b<<<dim3(DH / 32, S_LEN / 32, NH), tpb, 0, stream>>>(vb, vtb, S_LEN, DH);

  flash_attn<<<dim3(S_LEN / 64, NH), 256, 0, stream>>>(q1b, q2b, k1b, k2b, vtb, lamw, oa);

  // h = o @ Wo + xn  (fp32)
  gemm_a<1, 64><<<dim3(D_DIM / 64, S_LEN / 128, 1), 256, 0, stream>>>(
      oa, wot, nullptr, hf, xnf, S_LEN, D_DIM, NH * DH, 0, 0);
  // z = rmsnorm(h)
  rmsnorm_kernel<<<S_LEN, 256, 0, stream>>>(hf, g, nullptr, zb);
  // gate = silu(z@W1) * (z@W2)  (bf16)
  gemm_a<2, 64><<<dim3(HID / 64, S_LEN / 128, 1), 256, 0, stream>>>(
      zb, w1t, w2t, ffb, nullptr, S_LEN, HID, D_DIM, 0, 0);
  // out = gate @ W3 + h  (fp32)
  gemm_a<1, 64><<<dim3(D_DIM / 64, S_LEN / 128, 1), 256, 0, stream>>>(
      ffb, w3t, nullptr, d_out, hf, S_LEN, D_DIM, HID, 0, 0);
}

// Round 3
// 946.948 us; speedup vs baseline: 1.0338x; 1.0338x over previous
//
#include <hip/hip_runtime.h>

typedef unsigned short u16;
typedef __bf16 bf16x8 __attribute__((ext_vector_type(8)));
typedef float f32x4 __attribute__((ext_vector_type(4)));

#define S_LEN 2048
#define D_DIM 2048
#define NH 16
#define DH 128
#define HID 8192

__device__ __forceinline__ u16 f2bf(float f) {
  unsigned int u = __float_as_uint(f);
  u += 0x7fff + ((u >> 16) & 1);   // round-to-nearest-even
  return (u16)(u >> 16);
}

// async global->LDS, 16 bytes per lane (global_load_lds_dwordx4)
__device__ __forceinline__ void gld16(const u16* g, u16* l) {
  __builtin_amdgcn_global_load_lds(
      (const __attribute__((address_space(1))) unsigned int*)g,
      (__attribute__((address_space(3))) unsigned int*)l, 16, 0, 0);
}

// ---------------------------------------------------------------------------
// Transpose-convert: in [R][C] fp32 -> out [C][R] bf16, batched over blockIdx.z
// ---------------------------------------------------------------------------
__global__ __launch_bounds__(256) void tconv_f2b(const float* __restrict__ in,
                                                 u16* __restrict__ out, int R, int C) {
  __shared__ float tile[32][33];
  size_t boff = (size_t)blockIdx.z * R * C;
  in += boff; out += boff;
  int c0 = blockIdx.x * 32, r0 = blockIdx.y * 32;
  int tx = threadIdx.x, ty = threadIdx.y;
#pragma unroll
  for (int i = 0; i < 32; i += 8) tile[ty + i][tx] = in[(size_t)(r0 + ty + i) * C + c0 + tx];
  __syncthreads();
#pragma unroll
  for (int i = 0; i < 32; i += 8) out[(size_t)(c0 + ty + i) * R + r0 + tx] = f2bf(tile[tx][ty + i]);
}

// bf16 -> bf16 transpose (for V -> V^T)
__global__ __launch_bounds__(256) void tconv_b2b(const u16* __restrict__ in,
                                                 u16* __restrict__ out, int R, int C) {
  __shared__ u16 tile[32][34];
  size_t boff = (size_t)blockIdx.z * R * C;
  in += boff; out += boff;
  int c0 = blockIdx.x * 32, r0 = blockIdx.y * 32;
  int tx = threadIdx.x, ty = threadIdx.y;
#pragma unroll
  for (int i = 0; i < 32; i += 8) tile[ty + i][tx] = in[(size_t)(r0 + ty + i) * C + c0 + tx];
  __syncthreads();
#pragma unroll
  for (int i = 0; i < 32; i += 8) out[(size_t)(c0 + ty + i) * R + r0 + tx] = tile[tx][ty + i];
}

// ---------------------------------------------------------------------------
// RMSNorm: per-row (D=2048), writes fp32 (optional) and bf16
// ---------------------------------------------------------------------------
__global__ __launch_bounds__(256) void rmsnorm_kernel(const float* __restrict__ x,
                                                      const float* __restrict__ g,
                                                      float* __restrict__ xf,
                                                      u16* __restrict__ xb) {
  int row = blockIdx.x;
  int t = threadIdx.x;
  const float4* xr = (const float4*)(x + (size_t)row * D_DIM);
  float4 v0 = xr[t];
  float4 v1 = xr[t + 256];
  float ss = v0.x * v0.x + v0.y * v0.y + v0.z * v0.z + v0.w * v0.w +
             v1.x * v1.x + v1.y * v1.y + v1.z * v1.z + v1.w * v1.w;
#pragma unroll
  for (int o = 1; o < 64; o <<= 1) ss += __shfl_xor(ss, o, 64);
  __shared__ float wss[4];
  if ((t & 63) == 0) wss[t >> 6] = ss;
  __syncthreads();
  float tot = wss[0] + wss[1] + wss[2] + wss[3];
  float rs = rsqrtf(tot * (1.0f / D_DIM) + 1e-6f);
  const float4* gr = (const float4*)g;
  float4 g0 = gr[t], g1 = gr[t + 256];
  float4 o0, o1;
  o0.x = v0.x * rs * g0.x; o0.y = v0.y * rs * g0.y; o0.z = v0.z * rs * g0.z; o0.w = v0.w * rs * g0.w;
  o1.x = v1.x * rs * g1.x; o1.y = v1.y * rs * g1.y; o1.z = v1.z * rs * g1.z; o1.w = v1.w * rs * g1.w;
  if (xf) {
    float4* xfr = (float4*)(xf + (size_t)row * D_DIM);
    xfr[t] = o0; xfr[t + 256] = o1;
  }
  ushort4 b0, b1;
  b0.x = f2bf(o0.x); b0.y = f2bf(o0.y); b0.z = f2bf(o0.z); b0.w = f2bf(o0.w);
  b1.x = f2bf(o1.x); b1.y = f2bf(o1.y); b1.z = f2bf(o1.z); b1.w = f2bf(o1.w);
  ushort4* xbr = (ushort4*)(xb + (size_t)row * D_DIM);
  xbr[t] = b0; xbr[t + 256] = b1;
}

// ---------------------------------------------------------------------------
// lambda[h] = exp(lq1.lk1) - exp(lq2.lk2) + 0.8
// ---------------------------------------------------------------------------
__global__ __launch_bounds__(256) void lam_kernel(const float* __restrict__ lq1,
                                                  const float* __restrict__ lk1,
                                                  const float* __restrict__ lq2,
                                                  const float* __restrict__ lk2,
                                                  float* __restrict__ lamw) {
  int t = threadIdx.x;
  int h = t >> 4, i = (t & 15) << 3;
  float d1 = 0.f, d2 = 0.f;
#pragma unroll
  for (int j = 0; j < 8; j++) {
    d1 += lq1[h * DH + i + j] * lk1[h * DH + i + j];
    d2 += lq2[h * DH + i + j] * lk2[h * DH + i + j];
  }
#pragma unroll
  for (int o = 1; o < 16; o <<= 1) { d1 += __shfl_xor(d1, o, 64); d2 += __shfl_xor(d2, o, 64); }
  if ((t & 15) == 0) lamw[h] = __expf(d1) - __expf(d2) + 0.8f;
}

// ---------------------------------------------------------------------------
// gemm8p: phased-schedule projection GEMM (m201-style, plain HIP).
// C[M=2048, N=10240] = A[M,K] @ Wcat[N,K]^T, bf16. BM=256, BN=128, BK=64,
// 512 thr = 8 waves (2M x 4N), per-wave 128x32 output.
// 3-slot K-tile ring (144 KiB LDS), prefetch lead = 2 K-tiles.
// Per K-tile: 2 phases, each {ds_read frags | issue 3 gld | s_barrier |
//   lgkmcnt(0)+sched_barrier | setprio(1) 16xMFMA setprio(0) | s_barrier}.
// ONE counted vmcnt(6) per K-tile (k+1's 6 loads drained, k+2's in flight).
// Byte-XOR swizzle (row&7)<<4, both-sides (pre-swizzled global source +
// swizzled ds_read; linear gld dest).
// Epilogue permutes cols into [tensor*16+head][S][128] chunks.
// ---------------------------------------------------------------------------
__global__ __launch_bounds__(512, 2) void gemm8p(const u16* __restrict__ A,
                                                 const u16* __restrict__ Bt,
                                                 u16* __restrict__ Out, int K) {
  __shared__ __align__(16) u16 As[3][256 * 64];  // 3 x 32 KiB
  __shared__ __align__(16) u16 Bs[3][128 * 64];  // 3 x 16 KiB
  const int t = threadIdx.x;
  const int lane = t & 63, wid = t >> 6;
  const int wm = (wid >> 2) * 128, wn = (wid & 3) * 32;
  const int fr = lane & 15, fq = lane >> 4;
  const int n0 = blockIdx.x * 128, m0 = blockIdx.y * 256;

  f32x4 acc[8][2] = {};

  // staging map: batch s = 64 rows (8KB = 512 thr x 16B). thread t owns row
  // (s*64 + (t>>3)), physical bytes (t&7)*16. pre-swizzled global col:
  const int sro = t >> 3;
  const int scol = ((t & 7) ^ (sro & 7)) << 3;  // elem = swizzled byte col / 2
  const u16* aSrc = A + (size_t)(m0 + sro) * K + scol;
  const u16* bSrc = Bt + (size_t)(n0 + sro) * K + scol;
  const int NT = K >> 6;
  const int swz = (fr & 7) << 4;

#define PA(buf, kof, s) gld16(aSrc + (size_t)((s)*64) * K + (kof), &As[buf][(s)*4096 + t * 8])
#define PB(buf, kof, s) gld16(bSrc + (size_t)((s)*64) * K + (kof), &Bs[buf][(s)*4096 + t * 8])

  // prologue: stage ktile 0 and 1 (6 gld each)
  PA(0, 0, 0); PA(0, 0, 1); PB(0, 0, 0); PA(0, 0, 2); PA(0, 0, 3); PB(0, 0, 1);
  PA(1, 64, 0); PA(1, 64, 1); PB(1, 64, 0); PA(1, 64, 2); PA(1, 64, 3); PB(1, 64, 1);
  asm volatile("s_waitcnt vmcnt(6)" ::: "memory");
  __builtin_amdgcn_s_barrier();

  for (int k = 0; k < NT; ++k) {
    const int r = k % 3, pbuf = (k + 2) % 3;
    const bool pf = (k + 2) < NT;
    const int kof = (k + 2) << 6;

    bf16x8 bfr[2][2], af[4][2];
    // ---- phase 1: B frags + A(mh0) frags; stage 3; MFMA quadrant mh0 ----
#pragma unroll
    for (int j = 0; j < 2; ++j)
#pragma unroll
      for (int kk = 0; kk < 2; ++kk) {
        int row = wn + j * 16 + fr;
        int cb = (kk * 64 + fq * 16) ^ swz;
        bfr[j][kk] = *(const bf16x8*)&Bs[r][row * 64 + (cb >> 1)];
      }
#pragma unroll
    for (int i = 0; i < 4; ++i)
#pragma unroll
      for (int kk = 0; kk < 2; ++kk) {
        int row = wm + i * 16 + fr;
        int cb = (kk * 64 + fq * 16) ^ swz;
        af[i][kk] = *(const bf16x8*)&As[r][row * 64 + (cb >> 1)];
      }
    if (pf) { PA(pbuf, kof, 0); PA(pbuf, kof, 1); PB(pbuf, kof, 0); }
    __builtin_amdgcn_s_barrier();
    asm volatile("s_waitcnt lgkmcnt(0)" ::: "memory");
    __builtin_amdgcn_sched_barrier(0);
    __builtin_amdgcn_s_setprio(1);
#pragma unroll
    for (int i = 0; i < 4; ++i)
#pragma unroll
      for (int j = 0; j < 2; ++j) {
        acc[i][j] = __builtin_amdgcn_mfma_f32_16x16x32_bf16(af[i][0], bfr[j][0], acc[i][j], 0, 0, 0);
        acc[i][j] = __builtin_amdgcn_mfma_f32_16x16x32_bf16(af[i][1], bfr[j][1], acc[i][j], 0, 0, 0);
      }
    __builtin_amdgcn_s_setprio(0);
    __builtin_amdgcn_s_barrier();

    // ---- phase 2: A(mh1) frags; stage 3; MFMA quadrant mh1 ----
#pragma unroll
    for (int i = 0; i < 4; ++i)
#pragma unroll
      for (int kk = 0; kk < 2; ++kk) {
        int row = wm + 64 + i * 16 + fr;
        int cb = (kk * 64 + fq * 16) ^ swz;
        af[i][kk] = *(const bf16x8*)&As[r][row * 64 + (cb >> 1)];
      }
    if (pf) { PA(pbuf, kof, 2); PA(pbuf, kof, 3); PB(pbuf, kof, 1); }
    __builtin_amdgcn_s_barrier();
    asm volatile("s_waitcnt lgkmcnt(0)" ::: "memory");
    __builtin_amdgcn_sched_barrier(0);
    __builtin_amdgcn_s_setprio(1);
#pragma unroll
    for (int i = 0; i < 4; ++i)
#pragma unroll
      for (int j = 0; j < 2; ++j) {
        acc[4 + i][j] = __builtin_amdgcn_mfma_f32_16x16x32_bf16(af[i][0], bfr[j][0], acc[4 + i][j], 0, 0, 0);
        acc[4 + i][j] = __builtin_amdgcn_mfma_f32_16x16x32_bf16(af[i][1], bfr[j][1], acc[4 + i][j], 0, 0, 0);
      }
    __builtin_amdgcn_s_setprio(0);

    if (k + 1 < NT) {
      // drain ktile k+1's 6 loads; ktile k+2's 6 stay in flight
      if (pf) asm volatile("s_waitcnt vmcnt(6)" ::: "memory");
      else    asm volatile("s_waitcnt vmcnt(0)" ::: "memory");
      __builtin_amdgcn_s_barrier();
    }
  }
#undef PA
#undef PB

  // epilogue: permuted store into [tensor*16+head][S][128]
  const size_t headBase = (size_t)(n0 >> 7) * ((size_t)S_LEN * 128);
#pragma unroll
  for (int i8 = 0; i8 < 8; ++i8)
#pragma unroll
    for (int j = 0; j < 2; ++j) {
      int row0 = m0 + wm + (i8 >> 2) * 64 + (i8 & 3) * 16 + (fq << 2);
      int colL = wn + j * 16 + fr;
#pragma unroll
      for (int rr = 0; rr < 4; ++rr)
        Out[headBase + (size_t)(row0 + rr) * 128 + colL] = f2bf(acc[i8][j][rr]);
    }
}

// ---------------------------------------------------------------------------
// gemm8s: phased-schedule dual-B SwiGLU GEMM.
// out[M=2048, N=8192] = f2bf( silu(A@W1^T) * (A@W2^T) ), bf16 in.
// BM=128, BN=128, BK=64, 512 thr = 8 waves (2M x 4N), per-wave 64x32 each acc.
// LDS: 3-slot ring x (A 16K + B1 16K + B2 16K) = 144 KiB. Same cadence/ledger
// as gemm8p: 2 phases/ktile (ph1 acc1/W1, ph2 acc2/W2 with A-frag reuse),
// 3 gld/phase, one vmcnt(6) per ktile.
// ---------------------------------------------------------------------------
__global__ __launch_bounds__(512, 2) void gemm8s(const u16* __restrict__ A,
                                                 const u16* __restrict__ B1t,
                                                 const u16* __restrict__ B2t,
                                                 u16* __restrict__ Out, int N, int K) {
  __shared__ __align__(16) u16 As[3][128 * 64];
  __shared__ __align__(16) u16 B1s[3][128 * 64];
  __shared__ __align__(16) u16 B2s[3][128 * 64];
  const int t = threadIdx.x;
  const int lane = t & 63, wid = t >> 6;
  const int wm = (wid >> 2) * 64, wn = (wid & 3) * 32;
  const int fr = lane & 15, fq = lane >> 4;
  const int n0 = blockIdx.x * 128, m0 = blockIdx.y * 128;

  f32x4 acc1[4][2] = {};
  f32x4 acc2[4][2] = {};

  const int sro = t >> 3;
  const int scol = ((t & 7) ^ (sro & 7)) << 3;
  const u16* aSrc = A + (size_t)(m0 + sro) * K + scol;
  const u16* b1Src = B1t + (size_t)(n0 + sro) * K + scol;
  const u16* b2Src = B2t + (size_t)(n0 + sro) * K + scol;
  const int NT = K >> 6;
  const int swz = (fr & 7) << 4;

#define SA(buf, kof, s) gld16(aSrc + (size_t)((s)*64) * K + (kof), &As[buf][(s)*4096 + t * 8])
#define SB1(buf, kof, s) gld16(b1Src + (size_t)((s)*64) * K + (kof), &B1s[buf][(s)*4096 + t * 8])
#define SB2(buf, kof, s) gld16(b2Src + (size_t)((s)*64) * K + (kof), &B2s[buf][(s)*4096 + t * 8])

  SA(0, 0, 0); SA(0, 0, 1); SB1(0, 0, 0); SB1(0, 0, 1); SB2(0, 0, 0); SB2(0, 0, 1);
  SA(1, 64, 0); SA(1, 64, 1); SB1(1, 64, 0); SB1(1, 64, 1); SB2(1, 64, 0); SB2(1, 64, 1);
  asm volatile("s_waitcnt vmcnt(6)" ::: "memory");
  __builtin_amdgcn_s_barrier();

  for (int k = 0; k < NT; ++k) {
    const int r = k % 3, pbuf = (k + 2) % 3;
    const bool pf = (k + 2) < NT;
    const int kof = (k + 2) << 6;

    bf16x8 af[4][2], bfr[2][2];
    // ---- phase 1: A + B1 frags; stage 3; MFMA acc1 ----
#pragma unroll
    for (int i = 0; i < 4; ++i)
#pragma unroll
      for (int kk = 0; kk < 2; ++kk) {
        int row = wm + i * 16 + fr;
        int cb = (kk * 64 + fq * 16) ^ swz;
        af[i][kk] = *(const bf16x8*)&As[r][row * 64 + (cb >> 1)];
      }
#pragma unroll
    for (int j = 0; j < 2; ++j)
#pragma unroll
      for (int kk = 0; kk < 2; ++kk) {
        int row = wn + j * 16 + fr;
        int cb = (kk * 64 + fq * 16) ^ swz;
        bfr[j][kk] = *(const bf16x8*)&B1s[r][row * 64 + (cb >> 1)];
      }
    if (pf) { SA(pbuf, kof, 0); SA(pbuf, kof, 1); SB1(pbuf, kof, 0); }
    __builtin_amdgcn_s_barrier();
    asm volatile("s_waitcnt lgkmcnt(0)" ::: "memory");
    __builtin_amdgcn_sched_barrier(0);
    __builtin_amdgcn_s_setprio(1);
#pragma unroll
    for (int i = 0; i < 4; ++i)
#pragma unroll
      for (int j = 0; j < 2; ++j) {
        acc1[i][j] = __builtin_amdgcn_mfma_f32_16x16x32_bf16(af[i][0], bfr[j][0], acc1[i][j], 0, 0, 0);
        acc1[i][j] = __builtin_amdgcn_mfma_f32_16x16x32_bf16(af[i][1], bfr[j][1], acc1[i][j], 0, 0, 0);
      }
    __builtin_amdgcn_s_setprio(0);
    __builtin_amdgcn_s_barrier();

    // ---- phase 2: B2 frags (A reuse); stage 3; MFMA acc2 ----
#pragma unroll
    for (int j = 0; j < 2; ++j)
#pragma unroll
      for (int kk = 0; kk < 2; ++kk) {
        int row = wn + j * 16 + fr;
        int cb = (kk * 64 + fq * 16) ^ swz;
        bfr[j][kk] = *(const bf16x8*)&B2s[r][row * 64 + (cb >> 1)];
      }
    if (pf) { SB1(pbuf, kof, 1); SB2(pbuf, kof, 0); SB2(pbuf, kof, 1); }
    __builtin_amdgcn_s_barrier();
    asm volatile("s_waitcnt lgkmcnt(0)" ::: "memory");
    __builtin_amdgcn_sched_barrier(0);
    __builtin_amdgcn_s_setprio(1);
#pragma unroll
    for (int i = 0; i < 4; ++i)
#pragma unroll
      for (int j = 0; j < 2; ++j) {
        acc2[i][j] = __builtin_amdgcn_mfma_f32_16x16x32_bf16(af[i][0], bfr[j][0], acc2[i][j], 0, 0, 0);
        acc2[i][j] = __builtin_amdgcn_mfma_f32_16x16x32_bf16(af[i][1], bfr[j][1], acc2[i][j], 0, 0, 0);
      }
    __builtin_amdgcn_s_setprio(0);

    if (k + 1 < NT) {
      if (pf) asm volatile("s_waitcnt vmcnt(6)" ::: "memory");
      else    asm volatile("s_waitcnt vmcnt(0)" ::: "memory");
      __builtin_amdgcn_s_barrier();
    }
  }
#undef SA
#undef SB1
#undef SB2

#pragma unroll
  for (int i = 0; i < 4; ++i)
#pragma unroll
    for (int j = 0; j < 2; ++j) {
      int row0 = m0 + wm + i * 16 + (fq << 2);
      int col = n0 + wn + j * 16 + fr;
#pragma unroll
      for (int rr = 0; rr < 4; ++rr) {
        float v = acc1[i][j][rr];
        float g2 = acc2[i][j][rr];
        float sg = v / (1.0f + __expf(-v));
        Out[(size_t)(row0 + rr) * N + col] = f2bf(sg * g2);
      }
    }
}

// ---------------------------------------------------------------------------
// m97-style GEMM, 2-phase double-buffered (used for Wo and W3).
// MODE 1: fp32 out = acc + res
// ---------------------------------------------------------------------------
template <int MODE, int BN>
__global__ __launch_bounds__(256) void gemm_a(const u16* __restrict__ A,
                                              const u16* __restrict__ Bt,
                                              const u16* __restrict__ Bt2,
                                              void* __restrict__ Cout,
                                              const float* __restrict__ res,
                                              int M, int N, int K, long sBt, long sC) {
  constexpr int BM = 128, BK = 32;
  constexpr int JF = BN / 32;  // j-frags per wave
  __shared__ __align__(16) u16 As[2][BM * BK];
  __shared__ __align__(16) u16 Bs[2][BN * BK];
  const int t = threadIdx.x;
  const int lane = t & 63, wid = t >> 6;
  const int wm = (wid >> 1) * 64, wn = (wid & 1) * (BN / 2);
  const int fr = lane & 15, fq = lane >> 4;
  const int m0 = blockIdx.y * BM, n0 = blockIdx.x * BN;
  const int bz = blockIdx.z;
  const u16* bt = Bt + (long)bz * sBt;
  f32x4 acc[4][JF] = {};
  const int sr = t >> 2, sc = (t & 3) << 3;   // 16B-chunk row/col
  const u16* aG = A + (long)(m0 + sr) * K + sc;
  const u16* bG = bt + (long)(n0 + sr) * K + sc;

  auto stage = [&](int buf, int k0) {
    gld16(aG + k0, &As[buf][t * 8]);
    gld16(aG + (long)64 * K + k0, &As[buf][t * 8 + 64 * BK]);
    gld16(bG + k0, &Bs[buf][t * 8]);
    if (BN == 128) gld16(bG + (long)64 * K + k0, &Bs[buf][t * 8 + 64 * BK]);
  };

  stage(0, 0);
  __syncthreads();

  int cur = 0;
  for (int k0 = 0; k0 < K; k0 += BK) {
    if (k0 + BK < K) stage(cur ^ 1, k0 + BK);

    bf16x8 af[4], bfr[JF];
#pragma unroll
    for (int i = 0; i < 4; i++) af[i] = *(const bf16x8*)&As[cur][(wm + i * 16 + fr) * BK + fq * 8];
#pragma unroll
    for (int j = 0; j < JF; j++) bfr[j] = *(const bf16x8*)&Bs[cur][(wn + j * 16 + fr) * BK + fq * 8];

    __builtin_amdgcn_s_setprio(1);
#pragma unroll
    for (int i = 0; i < 4; i++)
#pragma unroll
      for (int j = 0; j < JF; j++)
        acc[i][j] = __builtin_amdgcn_mfma_f32_16x16x32_bf16(af[i], bfr[j], acc[i][j], 0, 0, 0);
    __builtin_amdgcn_s_setprio(0);

    __syncthreads();
    cur ^= 1;
  }

#pragma unroll
  for (int i = 0; i < 4; i++)
#pragma unroll
    for (int j = 0; j < JF; j++) {
      int row0 = m0 + wm + i * 16 + (fq << 2);
      int col = n0 + wn + j * 16 + fr;
#pragma unroll
      for (int r = 0; r < 4; r++) {
        long idx = (long)(row0 + r) * N + col;
        float v = acc[i][j][r];
        if (MODE == 1) {
          ((float*)Cout)[idx] = v + res[idx];
        } else {
          ((u16*)Cout + (long)bz * sC)[idx] = f2bf(v);
        }
      }
    }
}

// ---------------------------------------------------------------------------
// Differential flash attention, static softmax (scores bounded; no max track).
// Denominator l comes free from the matrix pipe: P x ones-fragment MFMA.
// One block per (64-query tile, head).
// q1,q2,k1,k2: [H][S][DH] bf16;  vt: [H][DH][S] bf16;  o: [S][H*DH] bf16
// ---------------------------------------------------------------------------
#define LDK 136
#define LDV 40
#define LDP 40

__global__ __launch_bounds__(256) void flash_attn(const u16* __restrict__ q1g,
                                                  const u16* __restrict__ q2g,
                                                  const u16* __restrict__ k1g,
                                                  const u16* __restrict__ k2g,
                                                  const u16* __restrict__ vtg,
                                                  const float* __restrict__ lamw,
                                                  u16* __restrict__ og) {
  __shared__ __align__(16) u16 Ks1[32 * LDK];
  __shared__ __align__(16) u16 Ks2[32 * LDK];
  __shared__ __align__(16) u16 Vs[128 * LDV];
  __shared__ __align__(16) u16 Ps[4 * 2 * 16 * LDP];
  const float scale = 0.08838834764831845f;  // 1/sqrt(128)
  int h = blockIdx.y, qt = blockIdx.x;
  size_t hoff = (size_t)h * S_LEN * DH;
  const u16* q1 = q1g + hoff;
  const u16* q2 = q2g + hoff;
  const u16* k1 = k1g + hoff;
  const u16* k2 = k2g + hoff;
  const u16* vt = vtg + hoff;
  int t = threadIdx.x, wid = t >> 6, lane = t & 63;
  int fr = lane & 15, fq = lane >> 4;
  int qrow = qt * 64 + wid * 16 + fr;
  bf16x8 qf1[4], qf2[4];
#pragma unroll
  for (int ks = 0; ks < 4; ks++) {
    qf1[ks] = *(const bf16x8*)&q1[(size_t)qrow * DH + ks * 32 + fq * 8];
    qf2[ks] = *(const bf16x8*)&q2[(size_t)qrow * DH + ks * 32 + fq * 8];
  }
  bf16x8 ones;
#pragma unroll
  for (int i = 0; i < 8; i++) ones[i] = (__bf16)1.0f;

  f32x4 O1[8] = {};
  f32x4 O2[8] = {};
  f32x4 L1 = {};
  f32x4 L2 = {};
  int skr = t >> 3, skc = (t & 7) << 4;
  int svr = t >> 2, svc = (t & 3) << 3;
  u16* myP1 = &Ps[(wid * 2 + 0) * 16 * LDP];
  u16* myP2 = &Ps[(wid * 2 + 1) * 16 * LDP];

  for (int kt = 0; kt < S_LEN; kt += 32) {
    uint4 ka1 = *(const uint4*)&k1[(size_t)(kt + skr) * DH + skc];
    uint4 kb1 = *(const uint4*)&k1[(size_t)(kt + skr) * DH + skc + 8];
    uint4 ka2 = *(const uint4*)&k2[(size_t)(kt + skr) * DH + skc];
    uint4 kb2 = *(const uint4*)&k2[(size_t)(kt + skr) * DH + skc + 8];
    uint4 va = *(const uint4*)&vt[(size_t)svr * S_LEN + kt + svc];
    uint4 vb = *(const uint4*)&vt[(size_t)(svr + 64) * S_LEN + kt + svc];
    __syncthreads();
    *(uint4*)&Ks1[skr * LDK + skc] = ka1;
    *(uint4*)&Ks1[skr * LDK + skc + 8] = kb1;
    *(uint4*)&Ks2[skr * LDK + skc] = ka2;
    *(uint4*)&Ks2[skr * LDK + skc + 8] = kb2;
    *(uint4*)&Vs[svr * LDV + svc] = va;
    *(uint4*)&Vs[(svr + 64) * LDV + svc] = vb;
    __syncthreads();

    f32x4 s1[2] = {};
    f32x4 s2[2] = {};
#pragma unroll
    for (int nf = 0; nf < 2; nf++)
#pragma unroll
      for (int ks = 0; ks < 4; ks++) {
        bf16x8 b1v = *(const bf16x8*)&Ks1[(nf * 16 + fr) * LDK + ks * 32 + fq * 8];
        s1[nf] = __builtin_amdgcn_mfma_f32_16x16x32_bf16(qf1[ks], b1v, s1[nf], 0, 0, 0);
        bf16x8 b2v = *(const bf16x8*)&Ks2[(nf * 16 + fr) * LDK + ks * 32 + fq * 8];
        s2[nf] = __builtin_amdgcn_mfma_f32_16x16x32_bf16(qf2[ks], b2v, s2[nf], 0, 0, 0);
      }

    // static softmax: p = exp(s*scale); no max subtraction, no rescale
#pragma unroll
    for (int nf = 0; nf < 2; nf++)
#pragma unroll
      for (int r = 0; r < 4; r++) {
        myP1[(fq * 4 + r) * LDP + nf * 16 + fr] = f2bf(__expf(s1[nf][r] * scale));
        myP2[(fq * 4 + r) * LDP + nf * 16 + fr] = f2bf(__expf(s2[nf][r] * scale));
      }
    asm volatile("s_waitcnt lgkmcnt(0)" ::: "memory");
    bf16x8 pa1 = *(const bf16x8*)&myP1[fr * LDP + fq * 8];
    bf16x8 pa2 = *(const bf16x8*)&myP2[fr * LDP + fq * 8];
    L1 = __builtin_amdgcn_mfma_f32_16x16x32_bf16(pa1, ones, L1, 0, 0, 0);
    L2 = __builtin_amdgcn_mfma_f32_16x16x32_bf16(pa2, ones, L2, 0, 0, 0);
#pragma unroll
    for (int f = 0; f < 8; f++) {
      bf16x8 bv = *(const bf16x8*)&Vs[(f * 16 + fr) * LDV + fq * 8];
      O1[f] = __builtin_amdgcn_mfma_f32_16x16x32_bf16(pa1, bv, O1[f], 0, 0, 0);
      O2[f] = __builtin_amdgcn_mfma_f32_16x16x32_bf16(pa2, bv, O2[f], 0, 0, 0);
    }
  }

  float lam = lamw[h];
#pragma unroll
  for (int r = 0; r < 4; r++) {
    float i1 = 1.0f / L1[r], i2 = lam / L2[r];
#pragma unroll
    for (int f = 0; f < 8; f++) {
      float val = O1[f][r] * i1 - O2[f][r] * i2;
      og[(size_t)(qt * 64 + wid * 16 + fq * 4 + r) * (NH * DH) + h * DH + f * 16 + fr] =
          f2bf(val);
    }
  }
}

// ---------------------------------------------------------------------------
extern "C" void kernel_launch(void* const* d_in, const int* in_sizes, int n_in,
                              void* d_out, int out_size, void* d_ws, size_t ws_size,
                              hipStream_t stream) {
  const float* x = (const float*)d_in[0];
  const float* g = (const float*)d_in[1];
  const float* Wq1 = (const float*)d_in[2];
  const float* Wq2 = (const float*)d_in[3];
  const float* Wk1 = (const float*)d_in[4];
  const float* Wk2 = (const float*)d_in[5];
  const float* Wv = (const float*)d_in[6];
  const float* lq1 = (const float*)d_in[7];
  const float* lk1 = (const float*)d_in[8];
  const float* lq2 = (const float*)d_in[9];
  const float* lk2 = (const float*)d_in[10];
  const float* Wo = (const float*)d_in[11];
  const float* W1 = (const float*)d_in[12];
  const float* W2 = (const float*)d_in[13];
  const float* W3 = (const float*)d_in[14];

  char* ws = (char*)d_ws;
  size_t off = 0;
  auto alloc = [&](size_t b) {
    char* p = ws + off;
    off += (b + 255) & ~(size_t)255;
    return p;
  };
  const size_t PROJ_B = (size_t)NH * DH * D_DIM * 2;  // 8.39 MB, 256-aligned
  // 5 proj weights contiguous -> one flattened N=10240 GEMM reads them as Wcat
  u16* wq1t = (u16*)alloc(PROJ_B);
  u16* wq2t = (u16*)alloc(PROJ_B);
  u16* wk1t = (u16*)alloc(PROJ_B);
  u16* wk2t = (u16*)alloc(PROJ_B);
  u16* wvt = (u16*)alloc(PROJ_B);
  u16* wot = (u16*)alloc((size_t)D_DIM * NH * DH * 2);
  u16* w1t = (u16*)alloc((size_t)HID * D_DIM * 2);
  u16* w2t = (u16*)alloc((size_t)HID * D_DIM * 2);
  u16* w3t = (u16*)alloc((size_t)D_DIM * HID * 2);
  u16* xnb = (u16*)alloc((size_t)S_LEN * D_DIM * 2);
  float* xnf = (float*)alloc((size_t)S_LEN * D_DIM * 4);
  // 5 proj outputs contiguous (q1,q2,k1,k2,v)
  u16* q1b = (u16*)alloc(PROJ_B);
  u16* q2b = (u16*)alloc(PROJ_B);
  u16* k1b = (u16*)alloc(PROJ_B);
  u16* k2b = (u16*)alloc(PROJ_B);
  u16* vb = (u16*)alloc(PROJ_B);
  u16* vtb = (u16*)alloc(PROJ_B);
  float* lamw = (float*)alloc(NH * 4);
  u16* oa = (u16*)alloc((size_t)S_LEN * NH * DH * 2);
  float* hf = (float*)alloc((size_t)S_LEN * D_DIM * 4);
  u16* zb = (u16*)alloc((size_t)S_LEN * D_DIM * 2);
  u16* ffb = (u16*)alloc((size_t)S_LEN * HID * 2);
  if (off > ws_size) return;  // workspace too small: out stays zero -> loud failure

  dim3 tpb(32, 8);
  // weight transposes (fp32 -> bf16, [K,N] -> [N,K])
  tconv_f2b<<<dim3(DH / 32, D_DIM / 32, NH), tpb, 0, stream>>>(Wq1, wq1t, D_DIM, DH);
  tconv_f2b<<<dim3(DH / 32, D_DIM / 32, NH), tpb, 0, stream>>>(Wq2, wq2t, D_DIM, DH);
  tconv_f2b<<<dim3(DH / 32, D_DIM / 32, NH), tpb, 0, stream>>>(Wk1, wk1t, D_DIM, DH);
  tconv_f2b<<<dim3(DH / 32, D_DIM / 32, NH), tpb, 0, stream>>>(Wk2, wk2t, D_DIM, DH);
  tconv_f2b<<<dim3(DH / 32, D_DIM / 32, NH), tpb, 0, stream>>>(Wv, wvt, D_DIM, DH);
  tconv_f2b<<<dim3(D_DIM / 32, (NH * DH) / 32, 1), tpb, 0, stream>>>(Wo, wot, NH * DH, D_DIM);
  tconv_f2b<<<dim3(HID / 32, D_DIM / 32, 1), tpb, 0, stream>>>(W1, w1t, D_DIM, HID);
  tconv_f2b<<<dim3(HID / 32, D_DIM / 32, 1), tpb, 0, stream>>>(W2, w2t, D_DIM, HID);
  tconv_f2b<<<dim3(D_DIM / 32, HID / 32, 1), tpb, 0, stream>>>(W3, w3t, HID, D_DIM);

  rmsnorm_kernel<<<S_LEN, 256, 0, stream>>>(x, g, xnf, xnb);
  lam_kernel<<<1, 256, 0, stream>>>(lq1, lk1, lq2, lk2, lamw);

  // all 5 projections as ONE flattened phased GEMM: N = 5*16*128 = 10240
  gemm8p<<<dim3((5 * NH * DH) / 128, S_LEN / 256), 512, 0, stream>>>(
      xnb, wq1t, q1b, D_DIM);
  // V -> V^T per head
  tconv_b2b<<<dim3(DH / 32, S_LEN / 32, NH), tpb, 0, stream>>>(vb, vtb, S_LEN, DH);

  flash_attn<<<dim3(S_LEN / 64, NH), 256, 0, stream>>>(q1b, q2b, k1b, k2b, vtb, lamw, oa);

  // h = o @ Wo + xn  (fp32)
  gemm_a<1, 64><<<dim3(D_DIM / 64, S_LEN / 128, 1), 256, 0, stream>>>(
      oa, wot, nullptr, hf, xnf, S_LEN, D_DIM, NH * DH, 0, 0);
  // z = rmsnorm(h)
  rmsnorm_kernel<<<S_LEN, 256, 0, stream>>>(hf, g, nullptr, zb);
  // gate = silu(z@W1) * (z@W2)  (bf16), phased dual-B GEMM
  gemm8s<<<dim3(HID / 128, S_LEN / 128), 512, 0, stream>>>(
      zb, w1t, w2t, ffb, HID, D_DIM);
  // out = gate @ W3 + h  (fp32)
  gemm_a<1, 64><<<dim3(D_DIM / 64, S_LEN / 128, 1), 256, 0, stream>>>(
      ffb, w3t, nullptr, d_out, hf, S_LEN, D_DIM, HID, 0, 0);
}

// Round 4
// 887.972 us; speedup vs baseline: 1.1025x; 1.0664x over previous
//
#include <hip/hip_runtime.h>

typedef unsigned short u16;
typedef __bf16 bf16x8 __attribute__((ext_vector_type(8)));
typedef float f32x4 __attribute__((ext_vector_type(4)));

#define S_LEN 2048
#define D_DIM 2048
#define NH 16
#define DH 128
#define HID 8192

__device__ __forceinline__ u16 f2bf(float f) {
  unsigned int u = __float_as_uint(f);
  u += 0x7fff + ((u >> 16) & 1);   // round-to-nearest-even
  return (u16)(u >> 16);
}

// async global->LDS, 16 bytes per lane (global_load_lds_dwordx4)
__device__ __forceinline__ void gld16(const u16* g, u16* l) {
  __builtin_amdgcn_global_load_lds(
      (const __attribute__((address_space(1))) unsigned int*)g,
      (__attribute__((address_space(3))) unsigned int*)l, 16, 0, 0);
}

// ---------------------------------------------------------------------------
// Transpose-convert: in [R][C] fp32 -> out [C][R] bf16, batched over blockIdx.z
// ---------------------------------------------------------------------------
__global__ __launch_bounds__(256) void tconv_f2b(const float* __restrict__ in,
                                                 u16* __restrict__ out, int R, int C) {
  __shared__ float tile[32][33];
  size_t boff = (size_t)blockIdx.z * R * C;
  in += boff; out += boff;
  int c0 = blockIdx.x * 32, r0 = blockIdx.y * 32;
  int tx = threadIdx.x, ty = threadIdx.y;
#pragma unroll
  for (int i = 0; i < 32; i += 8) tile[ty + i][tx] = in[(size_t)(r0 + ty + i) * C + c0 + tx];
  __syncthreads();
#pragma unroll
  for (int i = 0; i < 32; i += 8) out[(size_t)(c0 + ty + i) * R + r0 + tx] = f2bf(tile[tx][ty + i]);
}

// bf16 -> bf16 transpose (for V -> V^T)
__global__ __launch_bounds__(256) void tconv_b2b(const u16* __restrict__ in,
                                                 u16* __restrict__ out, int R, int C) {
  __shared__ u16 tile[32][34];
  size_t boff = (size_t)blockIdx.z * R * C;
  in += boff; out += boff;
  int c0 = blockIdx.x * 32, r0 = blockIdx.y * 32;
  int tx = threadIdx.x, ty = threadIdx.y;
#pragma unroll
  for (int i = 0; i < 32; i += 8) tile[ty + i][tx] = in[(size_t)(r0 + ty + i) * C + c0 + tx];
  __syncthreads();
#pragma unroll
  for (int i = 0; i < 32; i += 8) out[(size_t)(c0 + ty + i) * R + r0 + tx] = tile[tx][ty + i];
}

// ---------------------------------------------------------------------------
// RMSNorm: per-row (D=2048), writes fp32 (optional) and bf16
// ---------------------------------------------------------------------------
__global__ __launch_bounds__(256) void rmsnorm_kernel(const float* __restrict__ x,
                                                      const float* __restrict__ g,
                                                      float* __restrict__ xf,
                                                      u16* __restrict__ xb) {
  int row = blockIdx.x;
  int t = threadIdx.x;
  const float4* xr = (const float4*)(x + (size_t)row * D_DIM);
  float4 v0 = xr[t];
  float4 v1 = xr[t + 256];
  float ss = v0.x * v0.x + v0.y * v0.y + v0.z * v0.z + v0.w * v0.w +
             v1.x * v1.x + v1.y * v1.y + v1.z * v1.z + v1.w * v1.w;
#pragma unroll
  for (int o = 1; o < 64; o <<= 1) ss += __shfl_xor(ss, o, 64);
  __shared__ float wss[4];
  if ((t & 63) == 0) wss[t >> 6] = ss;
  __syncthreads();
  float tot = wss[0] + wss[1] + wss[2] + wss[3];
  float rs = rsqrtf(tot * (1.0f / D_DIM) + 1e-6f);
  const float4* gr = (const float4*)g;
  float4 g0 = gr[t], g1 = gr[t + 256];
  float4 o0, o1;
  o0.x = v0.x * rs * g0.x; o0.y = v0.y * rs * g0.y; o0.z = v0.z * rs * g0.z; o0.w = v0.w * rs * g0.w;
  o1.x = v1.x * rs * g1.x; o1.y = v1.y * rs * g1.y; o1.z = v1.z * rs * g1.z; o1.w = v1.w * rs * g1.w;
  if (xf) {
    float4* xfr = (float4*)(xf + (size_t)row * D_DIM);
    xfr[t] = o0; xfr[t + 256] = o1;
  }
  ushort4 b0, b1;
  b0.x = f2bf(o0.x); b0.y = f2bf(o0.y); b0.z = f2bf(o0.z); b0.w = f2bf(o0.w);
  b1.x = f2bf(o1.x); b1.y = f2bf(o1.y); b1.z = f2bf(o1.z); b1.w = f2bf(o1.w);
  ushort4* xbr = (ushort4*)(xb + (size_t)row * D_DIM);
  xbr[t] = b0; xbr[t + 256] = b1;
}

// ---------------------------------------------------------------------------
// lambda[h] = exp(lq1.lk1) - exp(lq2.lk2) + 0.8
// ---------------------------------------------------------------------------
__global__ __launch_bounds__(256) void lam_kernel(const float* __restrict__ lq1,
                                                  const float* __restrict__ lk1,
                                                  const float* __restrict__ lq2,
                                                  const float* __restrict__ lk2,
                                                  float* __restrict__ lamw) {
  int t = threadIdx.x;
  int h = t >> 4, i = (t & 15) << 3;
  float d1 = 0.f, d2 = 0.f;
#pragma unroll
  for (int j = 0; j < 8; j++) {
    d1 += lq1[h * DH + i + j] * lk1[h * DH + i + j];
    d2 += lq2[h * DH + i + j] * lk2[h * DH + i + j];
  }
#pragma unroll
  for (int o = 1; o < 16; o <<= 1) { d1 += __shfl_xor(d1, o, 64); d2 += __shfl_xor(d2, o, 64); }
  if ((t & 15) == 0) lamw[h] = __expf(d1) - __expf(d2) + 0.8f;
}

// ---------------------------------------------------------------------------
// gemm9: unified GEMM. m97 geometry (the measured-best reuse/TLP point):
//   256 thr = 4 waves (2M x 2N), per-wave 64x64 output, BM=BN=128, BK=32.
//   reads/MFMA = 0.5 (single-B) / 0.375 (dual-B: A-frags reused by both accs)
//   -> LDS BW (85 B/cyc, m134) no longer caps MfmaUtil (was 0.75 -> 33% cap).
// Ring-3 LDS (48K single / 72K dual) -> 3 (resp 2) blocks/CU of TLP.
// Counted vmcnt at tile boundary (stage k+2 during k; drain k+1 = vmcnt(4/6));
// never drains to 0 mid-loop. XOR swizzle (row&3)<<4 within 64B rows,
// both-sides (pre-swizzled global source + swizzled ds_read; linear gld dest).
// No mid-tile barriers / no sched pinning: compiler emits fine-grained lgkmcnt
// (m97 evidence) and interleaves staging with MFMA.
// MODE 0: bf16 out, permuted into [tensor*16+head][S][128] chunks (proj)
// MODE 1: fp32 out = acc + res
// MODE 2: dual-B; bf16 out = silu(acc1)*acc2
// ---------------------------------------------------------------------------
template <int MODE>
__global__ __launch_bounds__(256, (MODE == 2) ? 2 : 3)
void gemm9(const u16* __restrict__ A, const u16* __restrict__ Bt,
           const u16* __restrict__ Bt2, void* __restrict__ Cout,
           const float* __restrict__ res, int N, int K) {
  __shared__ __align__(16) u16 As[3][128 * 32];   // 3 x 8 KiB
  __shared__ __align__(16) u16 Bs[3][128 * 32];   // 3 x 8 KiB
  __shared__ __align__(16) u16 Bs2[(MODE == 2) ? 3 : 1][(MODE == 2) ? 128 * 32 : 8];
  const int t = threadIdx.x;
  const int lane = t & 63, wid = t >> 6;
  const int wm = (wid >> 1) * 64, wn = (wid & 1) * 64;
  const int fr = lane & 15, fq = lane >> 4;
  const int m0 = blockIdx.y * 128, n0 = blockIdx.x * 128;

  f32x4 acc[4][4] = {};
  f32x4 acc2[(MODE == 2) ? 4 : 1][(MODE == 2) ? 4 : 1] = {};

  // staging: slot = 64 rows x 64B; thread t -> row t>>2, physical 16B-chunk
  // (t&3). pre-swizzled source col so physical layout is logical^((row&3)<<4).
  const int sro = t >> 2;
  const int scol = ((t & 3) ^ (sro & 3)) << 3;  // elems
  const u16* aSrc = A + (size_t)(m0 + sro) * K + scol;
  const u16* bSrc = Bt + (size_t)(n0 + sro) * K + scol;
  const u16* b2Src = (MODE == 2) ? (Bt2 + (size_t)(n0 + sro) * K + scol) : nullptr;
  const int NT = K >> 5;

  auto stage = [&](int buf, int kof) {
    gld16(aSrc + kof, &As[buf][t * 8]);
    gld16(aSrc + (size_t)64 * K + kof, &As[buf][2048 + t * 8]);
    gld16(bSrc + kof, &Bs[buf][t * 8]);
    gld16(bSrc + (size_t)64 * K + kof, &Bs[buf][2048 + t * 8]);
    if constexpr (MODE == 2) {
      gld16(b2Src + kof, &Bs2[buf][t * 8]);
      gld16(b2Src + (size_t)64 * K + kof, &Bs2[buf][2048 + t * 8]);
    }
  };

  // prologue: stage tiles 0,1; wait tile 0 only (counted)
  stage(0, 0);
  stage(1, 32);
  if constexpr (MODE == 2) asm volatile("s_waitcnt vmcnt(6)" ::: "memory");
  else                     asm volatile("s_waitcnt vmcnt(4)" ::: "memory");
  __builtin_amdgcn_s_barrier();

  const int coff = ((fq << 4) ^ ((fr & 3) << 4)) >> 1;  // swizzled elem col

  for (int k = 0; k < NT; ++k) {
    const int r = k % 3, pbuf = (k + 2) % 3;
    const bool pf = (k + 2) < NT;

    bf16x8 af[4], bfr[4];
    bf16x8 b2fr[(MODE == 2) ? 4 : 1];
#pragma unroll
    for (int i = 0; i < 4; ++i)
      af[i] = *(const bf16x8*)&As[r][(wm + i * 16 + fr) * 32 + coff];
#pragma unroll
    for (int j = 0; j < 4; ++j)
      bfr[j] = *(const bf16x8*)&Bs[r][(wn + j * 16 + fr) * 32 + coff];
    if constexpr (MODE == 2) {
#pragma unroll
      for (int j = 0; j < 4; ++j)
        b2fr[j] = *(const bf16x8*)&Bs2[r][(wn + j * 16 + fr) * 32 + coff];
    }

    if (pf) stage(pbuf, (k + 2) << 5);

    __builtin_amdgcn_s_setprio(1);
#pragma unroll
    for (int i = 0; i < 4; ++i)
#pragma unroll
      for (int j = 0; j < 4; ++j)
        acc[i][j] = __builtin_amdgcn_mfma_f32_16x16x32_bf16(af[i], bfr[j], acc[i][j], 0, 0, 0);
    if constexpr (MODE == 2) {
#pragma unroll
      for (int i = 0; i < 4; ++i)
#pragma unroll
        for (int j = 0; j < 4; ++j)
          acc2[i][j] = __builtin_amdgcn_mfma_f32_16x16x32_bf16(af[i], b2fr[j], acc2[i][j], 0, 0, 0);
    }
    __builtin_amdgcn_s_setprio(0);

    if (k + 1 < NT) {
      if (pf) {
        if constexpr (MODE == 2) asm volatile("s_waitcnt vmcnt(6)" ::: "memory");
        else                     asm volatile("s_waitcnt vmcnt(4)" ::: "memory");
      } else {
        asm volatile("s_waitcnt vmcnt(0)" ::: "memory");
      }
      __builtin_amdgcn_s_barrier();
    }
  }

  // epilogue
  if constexpr (MODE == 0) {
    const size_t headBase = (size_t)(n0 >> 7) * ((size_t)S_LEN * 128);
#pragma unroll
    for (int i = 0; i < 4; ++i)
#pragma unroll
      for (int j = 0; j < 4; ++j) {
        int row0 = wm + i * 16 + (fq << 2) + m0;
        int colL = wn + j * 16 + fr;
#pragma unroll
        for (int rr = 0; rr < 4; ++rr)
          ((u16*)Cout)[headBase + (size_t)(row0 + rr) * 128 + colL] = f2bf(acc[i][j][rr]);
      }
  } else {
#pragma unroll
    for (int i = 0; i < 4; ++i)
#pragma unroll
      for (int j = 0; j < 4; ++j) {
        int row0 = m0 + wm + i * 16 + (fq << 2);
        int col = n0 + wn + j * 16 + fr;
#pragma unroll
        for (int rr = 0; rr < 4; ++rr) {
          size_t idx = (size_t)(row0 + rr) * N + col;
          float v = acc[i][j][rr];
          if constexpr (MODE == 1) {
            ((float*)Cout)[idx] = v + res[idx];
          } else {
            float g2 = acc2[i][j][rr];
            float sg = v / (1.0f + __expf(-v));
            ((u16*)Cout)[idx] = f2bf(sg * g2);
          }
        }
      }
  }
}

// ---------------------------------------------------------------------------
// Differential flash attention, static softmax (scores bounded; no max track).
// Denominator l comes free from the matrix pipe: P x ones-fragment MFMA.
// One block per (64-query tile, head).
// q1,q2,k1,k2: [H][S][DH] bf16;  vt: [H][DH][S] bf16;  o: [S][H*DH] bf16
// ---------------------------------------------------------------------------
#define LDK 136
#define LDV 40
#define LDP 40

__global__ __launch_bounds__(256) void flash_attn(const u16* __restrict__ q1g,
                                                  const u16* __restrict__ q2g,
                                                  const u16* __restrict__ k1g,
                                                  const u16* __restrict__ k2g,
                                                  const u16* __restrict__ vtg,
                                                  const float* __restrict__ lamw,
                                                  u16* __restrict__ og) {
  __shared__ __align__(16) u16 Ks1[32 * LDK];
  __shared__ __align__(16) u16 Ks2[32 * LDK];
  __shared__ __align__(16) u16 Vs[128 * LDV];
  __shared__ __align__(16) u16 Ps[4 * 2 * 16 * LDP];
  const float scale = 0.08838834764831845f;  // 1/sqrt(128)
  int h = blockIdx.y, qt = blockIdx.x;
  size_t hoff = (size_t)h * S_LEN * DH;
  const u16* q1 = q1g + hoff;
  const u16* q2 = q2g + hoff;
  const u16* k1 = k1g + hoff;
  const u16* k2 = k2g + hoff;
  const u16* vt = vtg + hoff;
  int t = threadIdx.x, wid = t >> 6, lane = t & 63;
  int fr = lane & 15, fq = lane >> 4;
  int qrow = qt * 64 + wid * 16 + fr;
  bf16x8 qf1[4], qf2[4];
#pragma unroll
  for (int ks = 0; ks < 4; ks++) {
    qf1[ks] = *(const bf16x8*)&q1[(size_t)qrow * DH + ks * 32 + fq * 8];
    qf2[ks] = *(const bf16x8*)&q2[(size_t)qrow * DH + ks * 32 + fq * 8];
  }
  bf16x8 ones;
#pragma unroll
  for (int i = 0; i < 8; i++) ones[i] = (__bf16)1.0f;

  f32x4 O1[8] = {};
  f32x4 O2[8] = {};
  f32x4 L1 = {};
  f32x4 L2 = {};
  int skr = t >> 3, skc = (t & 7) << 4;
  int svr = t >> 2, svc = (t & 3) << 3;
  u16* myP1 = &Ps[(wid * 2 + 0) * 16 * LDP];
  u16* myP2 = &Ps[(wid * 2 + 1) * 16 * LDP];

  for (int kt = 0; kt < S_LEN; kt += 32) {
    uint4 ka1 = *(const uint4*)&k1[(size_t)(kt + skr) * DH + skc];
    uint4 kb1 = *(const uint4*)&k1[(size_t)(kt + skr) * DH + skc + 8];
    uint4 ka2 = *(const uint4*)&k2[(size_t)(kt + skr) * DH + skc];
    uint4 kb2 = *(const uint4*)&k2[(size_t)(kt + skr) * DH + skc + 8];
    uint4 va = *(const uint4*)&vt[(size_t)svr * S_LEN + kt + svc];
    uint4 vb = *(const uint4*)&vt[(size_t)(svr + 64) * S_LEN + kt + svc];
    __syncthreads();
    *(uint4*)&Ks1[skr * LDK + skc] = ka1;
    *(uint4*)&Ks1[skr * LDK + skc + 8] = kb1;
    *(uint4*)&Ks2[skr * LDK + skc] = ka2;
    *(uint4*)&Ks2[skr * LDK + skc + 8] = kb2;
    *(uint4*)&Vs[svr * LDV + svc] = va;
    *(uint4*)&Vs[(svr + 64) * LDV + svc] = vb;
    __syncthreads();

    f32x4 s1[2] = {};
    f32x4 s2[2] = {};
#pragma unroll
    for (int nf = 0; nf < 2; nf++)
#pragma unroll
      for (int ks = 0; ks < 4; ks++) {
        bf16x8 b1v = *(const bf16x8*)&Ks1[(nf * 16 + fr) * LDK + ks * 32 + fq * 8];
        s1[nf] = __builtin_amdgcn_mfma_f32_16x16x32_bf16(qf1[ks], b1v, s1[nf], 0, 0, 0);
        bf16x8 b2v = *(const bf16x8*)&Ks2[(nf * 16 + fr) * LDK + ks * 32 + fq * 8];
        s2[nf] = __builtin_amdgcn_mfma_f32_16x16x32_bf16(qf2[ks], b2v, s2[nf], 0, 0, 0);
      }

    // static softmax: p = exp(s*scale); no max subtraction, no rescale
#pragma unroll
    for (int nf = 0; nf < 2; nf++)
#pragma unroll
      for (int r = 0; r < 4; r++) {
        myP1[(fq * 4 + r) * LDP + nf * 16 + fr] = f2bf(__expf(s1[nf][r] * scale));
        myP2[(fq * 4 + r) * LDP + nf * 16 + fr] = f2bf(__expf(s2[nf][r] * scale));
      }
    asm volatile("s_waitcnt lgkmcnt(0)" ::: "memory");
    bf16x8 pa1 = *(const bf16x8*)&myP1[fr * LDP + fq * 8];
    bf16x8 pa2 = *(const bf16x8*)&myP2[fr * LDP + fq * 8];
    L1 = __builtin_amdgcn_mfma_f32_16x16x32_bf16(pa1, ones, L1, 0, 0, 0);
    L2 = __builtin_amdgcn_mfma_f32_16x16x32_bf16(pa2, ones, L2, 0, 0, 0);
#pragma unroll
    for (int f = 0; f < 8; f++) {
      bf16x8 bv = *(const bf16x8*)&Vs[(f * 16 + fr) * LDV + fq * 8];
      O1[f] = __builtin_amdgcn_mfma_f32_16x16x32_bf16(pa1, bv, O1[f], 0, 0, 0);
      O2[f] = __builtin_amdgcn_mfma_f32_16x16x32_bf16(pa2, bv, O2[f], 0, 0, 0);
    }
  }

  float lam = lamw[h];
#pragma unroll
  for (int r = 0; r < 4; r++) {
    float i1 = 1.0f / L1[r], i2 = lam / L2[r];
#pragma unroll
    for (int f = 0; f < 8; f++) {
      float val = O1[f][r] * i1 - O2[f][r] * i2;
      og[(size_t)(qt * 64 + wid * 16 + fq * 4 + r) * (NH * DH) + h * DH + f * 16 + fr] =
          f2bf(val);
    }
  }
}

// ---------------------------------------------------------------------------
extern "C" void kernel_launch(void* const* d_in, const int* in_sizes, int n_in,
                              void* d_out, int out_size, void* d_ws, size_t ws_size,
                              hipStream_t stream) {
  const float* x = (const float*)d_in[0];
  const float* g = (const float*)d_in[1];
  const float* Wq1 = (const float*)d_in[2];
  const float* Wq2 = (const float*)d_in[3];
  const float* Wk1 = (const float*)d_in[4];
  const float* Wk2 = (const float*)d_in[5];
  const float* Wv = (const float*)d_in[6];
  const float* lq1 = (const float*)d_in[7];
  const float* lk1 = (const float*)d_in[8];
  const float* lq2 = (const float*)d_in[9];
  const float* lk2 = (const float*)d_in[10];
  const float* Wo = (const float*)d_in[11];
  const float* W1 = (const float*)d_in[12];
  const float* W2 = (const float*)d_in[13];
  const float* W3 = (const float*)d_in[14];

  char* ws = (char*)d_ws;
  size_t off = 0;
  auto alloc = [&](size_t b) {
    char* p = ws + off;
    off += (b + 255) & ~(size_t)255;
    return p;
  };
  const size_t PROJ_B = (size_t)NH * DH * D_DIM * 2;  // 8.39 MB, 256-aligned
  // 5 proj weights contiguous -> one flattened N=10240 GEMM reads them as Wcat
  u16* wq1t = (u16*)alloc(PROJ_B);
  u16* wq2t = (u16*)alloc(PROJ_B);
  u16* wk1t = (u16*)alloc(PROJ_B);
  u16* wk2t = (u16*)alloc(PROJ_B);
  u16* wvt = (u16*)alloc(PROJ_B);
  u16* wot = (u16*)alloc((size_t)D_DIM * NH * DH * 2);
  u16* w1t = (u16*)alloc((size_t)HID * D_DIM * 2);
  u16* w2t = (u16*)alloc((size_t)HID * D_DIM * 2);
  u16* w3t = (u16*)alloc((size_t)D_DIM * HID * 2);
  u16* xnb = (u16*)alloc((size_t)S_LEN * D_DIM * 2);
  float* xnf = (float*)alloc((size_t)S_LEN * D_DIM * 4);
  // 5 proj outputs contiguous (q1,q2,k1,k2,v)
  u16* q1b = (u16*)alloc(PROJ_B);
  u16* q2b = (u16*)alloc(PROJ_B);
  u16* k1b = (u16*)alloc(PROJ_B);
  u16* k2b = (u16*)alloc(PROJ_B);
  u16* vb = (u16*)alloc(PROJ_B);
  u16* vtb = (u16*)alloc(PROJ_B);
  float* lamw = (float*)alloc(NH * 4);
  u16* oa = (u16*)alloc((size_t)S_LEN * NH * DH * 2);
  float* hf = (float*)alloc((size_t)S_LEN * D_DIM * 4);
  u16* zb = (u16*)alloc((size_t)S_LEN * D_DIM * 2);
  u16* ffb = (u16*)alloc((size_t)S_LEN * HID * 2);
  if (off > ws_size) return;  // workspace too small: out stays zero -> loud failure

  dim3 tpb(32, 8);
  // weight transposes (fp32 -> bf16, [K,N] -> [N,K])
  tconv_f2b<<<dim3(DH / 32, D_DIM / 32, NH), tpb, 0, stream>>>(Wq1, wq1t, D_DIM, DH);
  tconv_f2b<<<dim3(DH / 32, D_DIM / 32, NH), tpb, 0, stream>>>(Wq2, wq2t, D_DIM, DH);
  tconv_f2b<<<dim3(DH / 32, D_DIM / 32, NH), tpb, 0, stream>>>(Wk1, wk1t, D_DIM, DH);
  tconv_f2b<<<dim3(DH / 32, D_DIM / 32, NH), tpb, 0, stream>>>(Wk2, wk2t, D_DIM, DH);
  tconv_f2b<<<dim3(DH / 32, D_DIM / 32, NH), tpb, 0, stream>>>(Wv, wvt, D_DIM, DH);
  tconv_f2b<<<dim3(D_DIM / 32, (NH * DH) / 32, 1), tpb, 0, stream>>>(Wo, wot, NH * DH, D_DIM);
  tconv_f2b<<<dim3(HID / 32, D_DIM / 32, 1), tpb, 0, stream>>>(W1, w1t, D_DIM, HID);
  tconv_f2b<<<dim3(HID / 32, D_DIM / 32, 1), tpb, 0, stream>>>(W2, w2t, D_DIM, HID);
  tconv_f2b<<<dim3(D_DIM / 32, HID / 32, 1), tpb, 0, stream>>>(W3, w3t, HID, D_DIM);

  rmsnorm_kernel<<<S_LEN, 256, 0, stream>>>(x, g, xnf, xnb);
  lam_kernel<<<1, 256, 0, stream>>>(lq1, lk1, lq2, lk2, lamw);

  // all 5 projections as ONE flattened GEMM: N = 5*16*128 = 10240
  gemm9<0><<<dim3((5 * NH * DH) / 128, S_LEN / 128), 256, 0, stream>>>(
      xnb, wq1t, nullptr, q1b, nullptr, 5 * NH * DH, D_DIM);
  // V -> V^T per head
  tconv_b2b<<<dim3(DH / 32, S_LEN / 32, NH), tpb, 0, stream>>>(vb, vtb, S_LEN, DH);

  flash_attn<<<dim3(S_LEN / 64, NH), 256, 0, stream>>>(q1b, q2b, k1b, k2b, vtb, lamw, oa);

  // h = o @ Wo + xn  (fp32)
  gemm9<1><<<dim3(D_DIM / 128, S_LEN / 128), 256, 0, stream>>>(
      oa, wot, nullptr, hf, xnf, D_DIM, NH * DH);
  // z = rmsnorm(h)
  rmsnorm_kernel<<<S_LEN, 256, 0, stream>>>(hf, g, nullptr, zb);
  // gate = silu(z@W1) * (z@W2)  (bf16), dual-B
  gemm9<2><<<dim3(HID / 128, S_LEN / 128), 256, 0, stream>>>(
      zb, w1t, w2t, ffb, nullptr, HID, D_DIM);
  // out = gate @ W3 + h  (fp32)
  gemm9<1><<<dim3(D_DIM / 128, S_LEN / 128), 256, 0, stream>>>(
      ffb, w3t, nullptr, d_out, hf, D_DIM, HID);
}

// Round 5
// 885.468 us; speedup vs baseline: 1.1056x; 1.0028x over previous
//
#include <hip/hip_runtime.h>

typedef unsigned short u16;
typedef __bf16 bf16x8 __attribute__((ext_vector_type(8)));
typedef float f32x4 __attribute__((ext_vector_type(4)));

#define S_LEN 2048
#define D_DIM 2048
#define NH 16
#define DH 128
#define HID 8192

__device__ __forceinline__ u16 f2bf(float f) {
  unsigned int u = __float_as_uint(f);
  u += 0x7fff + ((u >> 16) & 1);   // round-to-nearest-even
  return (u16)(u >> 16);
}

// async global->LDS, 16 bytes per lane (global_load_lds_dwordx4)
__device__ __forceinline__ void gld16(const u16* g, u16* l) {
  __builtin_amdgcn_global_load_lds(
      (const __attribute__((address_space(1))) unsigned int*)g,
      (__attribute__((address_space(3))) unsigned int*)l, 16, 0, 0);
}

// ---------------------------------------------------------------------------
// Transpose-convert: in [R][C] fp32 -> out [C][R] bf16, batched over blockIdx.z
// ---------------------------------------------------------------------------
__global__ __launch_bounds__(256) void tconv_f2b(const float* __restrict__ in,
                                                 u16* __restrict__ out, int R, int C) {
  __shared__ float tile[32][33];
  size_t boff = (size_t)blockIdx.z * R * C;
  in += boff; out += boff;
  int c0 = blockIdx.x * 32, r0 = blockIdx.y * 32;
  int tx = threadIdx.x, ty = threadIdx.y;
#pragma unroll
  for (int i = 0; i < 32; i += 8) tile[ty + i][tx] = in[(size_t)(r0 + ty + i) * C + c0 + tx];
  __syncthreads();
#pragma unroll
  for (int i = 0; i < 32; i += 8) out[(size_t)(c0 + ty + i) * R + r0 + tx] = f2bf(tile[tx][ty + i]);
}

// bf16 -> bf16 transpose (for V -> V^T)
__global__ __launch_bounds__(256) void tconv_b2b(const u16* __restrict__ in,
                                                 u16* __restrict__ out, int R, int C) {
  __shared__ u16 tile[32][34];
  size_t boff = (size_t)blockIdx.z * R * C;
  in += boff; out += boff;
  int c0 = blockIdx.x * 32, r0 = blockIdx.y * 32;
  int tx = threadIdx.x, ty = threadIdx.y;
#pragma unroll
  for (int i = 0; i < 32; i += 8) tile[ty + i][tx] = in[(size_t)(r0 + ty + i) * C + c0 + tx];
  __syncthreads();
#pragma unroll
  for (int i = 0; i < 32; i += 8) out[(size_t)(c0 + ty + i) * R + r0 + tx] = tile[tx][ty + i];
}

// ---------------------------------------------------------------------------
// RMSNorm: per-row (D=2048), writes fp32 (optional) and bf16
// ---------------------------------------------------------------------------
__global__ __launch_bounds__(256) void rmsnorm_kernel(const float* __restrict__ x,
                                                      const float* __restrict__ g,
                                                      float* __restrict__ xf,
                                                      u16* __restrict__ xb) {
  int row = blockIdx.x;
  int t = threadIdx.x;
  const float4* xr = (const float4*)(x + (size_t)row * D_DIM);
  float4 v0 = xr[t];
  float4 v1 = xr[t + 256];
  float ss = v0.x * v0.x + v0.y * v0.y + v0.z * v0.z + v0.w * v0.w +
             v1.x * v1.x + v1.y * v1.y + v1.z * v1.z + v1.w * v1.w;
#pragma unroll
  for (int o = 1; o < 64; o <<= 1) ss += __shfl_xor(ss, o, 64);
  __shared__ float wss[4];
  if ((t & 63) == 0) wss[t >> 6] = ss;
  __syncthreads();
  float tot = wss[0] + wss[1] + wss[2] + wss[3];
  float rs = rsqrtf(tot * (1.0f / D_DIM) + 1e-6f);
  const float4* gr = (const float4*)g;
  float4 g0 = gr[t], g1 = gr[t + 256];
  float4 o0, o1;
  o0.x = v0.x * rs * g0.x; o0.y = v0.y * rs * g0.y; o0.z = v0.z * rs * g0.z; o0.w = v0.w * rs * g0.w;
  o1.x = v1.x * rs * g1.x; o1.y = v1.y * rs * g1.y; o1.z = v1.z * rs * g1.z; o1.w = v1.w * rs * g1.w;
  if (xf) {
    float4* xfr = (float4*)(xf + (size_t)row * D_DIM);
    xfr[t] = o0; xfr[t + 256] = o1;
  }
  ushort4 b0, b1;
  b0.x = f2bf(o0.x); b0.y = f2bf(o0.y); b0.z = f2bf(o0.z); b0.w = f2bf(o0.w);
  b1.x = f2bf(o1.x); b1.y = f2bf(o1.y); b1.z = f2bf(o1.z); b1.w = f2bf(o1.w);
  ushort4* xbr = (ushort4*)(xb + (size_t)row * D_DIM);
  xbr[t] = b0; xbr[t + 256] = b1;
}

// ---------------------------------------------------------------------------
// lambda[h] = exp(lq1.lk1) - exp(lq2.lk2) + 0.8
// ---------------------------------------------------------------------------
__global__ __launch_bounds__(256) void lam_kernel(const float* __restrict__ lq1,
                                                  const float* __restrict__ lk1,
                                                  const float* __restrict__ lq2,
                                                  const float* __restrict__ lk2,
                                                  float* __restrict__ lamw) {
  int t = threadIdx.x;
  int h = t >> 4, i = (t & 15) << 3;
  float d1 = 0.f, d2 = 0.f;
#pragma unroll
  for (int j = 0; j < 8; j++) {
    d1 += lq1[h * DH + i + j] * lk1[h * DH + i + j];
    d2 += lq2[h * DH + i + j] * lk2[h * DH + i + j];
  }
#pragma unroll
  for (int o = 1; o < 16; o <<= 1) { d1 += __shfl_xor(d1, o, 64); d2 += __shfl_xor(d2, o, 64); }
  if ((t & 15) == 0) lamw[h] = __expf(d1) - __expf(d2) + 0.8f;
}

// ---------------------------------------------------------------------------
// combine2: out = P[0] + P[1] + res  (fp32, float4-vectorized)
// ---------------------------------------------------------------------------
__global__ __launch_bounds__(256) void combine2(const float* __restrict__ P,
                                                const float* __restrict__ res,
                                                float* __restrict__ out, int n4) {
  int i = blockIdx.x * 256 + threadIdx.x;
  if (i >= n4) return;
  float4 a = ((const float4*)P)[i];
  float4 b = ((const float4*)P)[i + n4];
  float4 r = ((const float4*)res)[i];
  float4 o;
  o.x = a.x + b.x + r.x; o.y = a.y + b.y + r.y;
  o.z = a.z + b.z + r.z; o.w = a.w + b.w + r.w;
  ((float4*)out)[i] = o;
}

// ---------------------------------------------------------------------------
// gemm9: unified GEMM. m97 geometry: 256 thr = 4 waves (2M x 2N), per-wave
// 64x64 output, BM=BN=128, BK=32 (64B LDS rows). Ring-3 LDS, counted vmcnt
// at tile boundary (stage k+2 during k; drain k+1), never 0 mid-loop.
// LDS swizzle for 64B rows: physical 16B-slot = logical ^ ((row>>1)&3).
//   (the (row&3) variant used for 128B rows is a 4-way conflict here: a 64B
//   row spans only half the banks. bank-quad = (4*fr + (fq^sig)) mod 8 with
//   sig=(fr>>1)&3 covers all 8 quads exactly 2x per 16-lane group = free.)
// Applied both-sides: pre-swizzled global source + swizzled ds_read; linear
// gld16 dest (rule #21).
// MODE 0: bf16 out, permuted into [tensor*16+head][S][128] chunks (proj)
// MODE 1: fp32 out = acc + res
// MODE 2: dual-B; bf16 out = silu(acc1)*acc2
// MODE 3: split-K partial: fp32 P[z][M][N] = acc   (z = blockIdx.z, A/B col
//         offset z*K; ld = true row stride)
// ---------------------------------------------------------------------------
template <int MODE>
__global__ __launch_bounds__(256, (MODE == 2) ? 2 : 3)
void gemm9(const u16* __restrict__ A, const u16* __restrict__ Bt,
           const u16* __restrict__ Bt2, void* __restrict__ Cout,
           const float* __restrict__ res, int N, int K, int ld) {
  __shared__ __align__(16) u16 As[3][128 * 32];   // 3 x 8 KiB
  __shared__ __align__(16) u16 Bs[3][128 * 32];   // 3 x 8 KiB
  __shared__ __align__(16) u16 Bs2[(MODE == 2) ? 3 : 1][(MODE == 2) ? 128 * 32 : 8];
  const int t = threadIdx.x;
  const int lane = t & 63, wid = t >> 6;
  const int wm = (wid >> 1) * 64, wn = (wid & 1) * 64;
  const int fr = lane & 15, fq = lane >> 4;
  const int m0 = blockIdx.y * 128, n0 = blockIdx.x * 128;
  const int kbase = (MODE == 3) ? (int)blockIdx.z * K : 0;

  f32x4 acc[4][4] = {};
  f32x4 acc2[(MODE == 2) ? 4 : 1][(MODE == 2) ? 4 : 1] = {};

  // staging: slot = 64 rows x 64B; thread t -> row t>>2, physical 16B-chunk
  // (t&3). pre-swizzled source chunk = (t&3) ^ ((row>>1)&3).
  const int sro = t >> 2;
  const int scol = (((t & 3) ^ ((sro >> 1) & 3)) << 3);  // elems
  const u16* aSrc = A + (size_t)(m0 + sro) * ld + kbase + scol;
  const u16* bSrc = Bt + (size_t)(n0 + sro) * ld + kbase + scol;
  const u16* b2Src = (MODE == 2) ? (Bt2 + (size_t)(n0 + sro) * ld + kbase + scol) : nullptr;
  const int NT = K >> 5;

  auto stage = [&](int buf, int kof) {
    gld16(aSrc + kof, &As[buf][t * 8]);
    gld16(aSrc + (size_t)64 * ld + kof, &As[buf][2048 + t * 8]);
    gld16(bSrc + kof, &Bs[buf][t * 8]);
    gld16(bSrc + (size_t)64 * ld + kof, &Bs[buf][2048 + t * 8]);
    if constexpr (MODE == 2) {
      gld16(b2Src + kof, &Bs2[buf][t * 8]);
      gld16(b2Src + (size_t)64 * ld + kof, &Bs2[buf][2048 + t * 8]);
    }
  };

  // prologue: stage tiles 0,1; wait tile 0 only (counted)
  stage(0, 0);
  stage(1, 32);
  if constexpr (MODE == 2) asm volatile("s_waitcnt vmcnt(6)" ::: "memory");
  else                     asm volatile("s_waitcnt vmcnt(4)" ::: "memory");
  __builtin_amdgcn_s_barrier();

  // read-side: logical 16B-slot fq -> physical fq ^ ((fr>>1)&3)
  const int coff = ((fq ^ ((fr >> 1) & 3)) << 3);  // elems

  for (int k = 0; k < NT; ++k) {
    const int r = k % 3, pbuf = (k + 2) % 3;
    const bool pf = (k + 2) < NT;

    bf16x8 af[4], bfr[4];
    bf16x8 b2fr[(MODE == 2) ? 4 : 1];
#pragma unroll
    for (int i = 0; i < 4; ++i)
      af[i] = *(const bf16x8*)&As[r][(wm + i * 16 + fr) * 32 + coff];
#pragma unroll
    for (int j = 0; j < 4; ++j)
      bfr[j] = *(const bf16x8*)&Bs[r][(wn + j * 16 + fr) * 32 + coff];
    if constexpr (MODE == 2) {
#pragma unroll
      for (int j = 0; j < 4; ++j)
        b2fr[j] = *(const bf16x8*)&Bs2[r][(wn + j * 16 + fr) * 32 + coff];
    }

    if (pf) stage(pbuf, (k + 2) << 5);

    __builtin_amdgcn_s_setprio(1);
#pragma unroll
    for (int i = 0; i < 4; ++i)
#pragma unroll
      for (int j = 0; j < 4; ++j)
        acc[i][j] = __builtin_amdgcn_mfma_f32_16x16x32_bf16(af[i], bfr[j], acc[i][j], 0, 0, 0);
    if constexpr (MODE == 2) {
#pragma unroll
      for (int i = 0; i < 4; ++i)
#pragma unroll
        for (int j = 0; j < 4; ++j)
          acc2[i][j] = __builtin_amdgcn_mfma_f32_16x16x32_bf16(af[i], b2fr[j], acc2[i][j], 0, 0, 0);
    }
    __builtin_amdgcn_s_setprio(0);

    if (k + 1 < NT) {
      if (pf) {
        if constexpr (MODE == 2) asm volatile("s_waitcnt vmcnt(6)" ::: "memory");
        else                     asm volatile("s_waitcnt vmcnt(4)" ::: "memory");
      } else {
        asm volatile("s_waitcnt vmcnt(0)" ::: "memory");
      }
      __builtin_amdgcn_s_barrier();
    }
  }

  // epilogue
  if constexpr (MODE == 0) {
    const size_t headBase = (size_t)(n0 >> 7) * ((size_t)S_LEN * 128);
#pragma unroll
    for (int i = 0; i < 4; ++i)
#pragma unroll
      for (int j = 0; j < 4; ++j) {
        int row0 = wm + i * 16 + (fq << 2) + m0;
        int colL = wn + j * 16 + fr;
#pragma unroll
        for (int rr = 0; rr < 4; ++rr)
          ((u16*)Cout)[headBase + (size_t)(row0 + rr) * 128 + colL] = f2bf(acc[i][j][rr]);
      }
  } else {
    const size_t zoff = (MODE == 3)
        ? (size_t)blockIdx.z * (size_t)gridDim.y * 128 * (size_t)N : 0;
#pragma unroll
    for (int i = 0; i < 4; ++i)
#pragma unroll
      for (int j = 0; j < 4; ++j) {
        int row0 = m0 + wm + i * 16 + (fq << 2);
        int col = n0 + wn + j * 16 + fr;
#pragma unroll
        for (int rr = 0; rr < 4; ++rr) {
          size_t idx = (size_t)(row0 + rr) * N + col;
          float v = acc[i][j][rr];
          if constexpr (MODE == 1) {
            ((float*)Cout)[idx] = v + res[idx];
          } else if constexpr (MODE == 3) {
            ((float*)Cout)[zoff + idx] = v;
          } else {
            float g2 = acc2[i][j][rr];
            float sg = v / (1.0f + __expf(-v));
            ((u16*)Cout)[idx] = f2bf(sg * g2);
          }
        }
      }
  }
}

// ---------------------------------------------------------------------------
// Differential flash attention, static softmax (scores bounded; no max track).
// Denominator l comes free from the matrix pipe: P x ones-fragment MFMA.
// One block per (64-query tile, head).
// q1,q2,k1,k2: [H][S][DH] bf16;  vt: [H][DH][S] bf16;  o: [S][H*DH] bf16
// ---------------------------------------------------------------------------
#define LDK 136
#define LDV 40
#define LDP 40

__global__ __launch_bounds__(256) void flash_attn(const u16* __restrict__ q1g,
                                                  const u16* __restrict__ q2g,
                                                  const u16* __restrict__ k1g,
                                                  const u16* __restrict__ k2g,
                                                  const u16* __restrict__ vtg,
                                                  const float* __restrict__ lamw,
                                                  u16* __restrict__ og) {
  __shared__ __align__(16) u16 Ks1[32 * LDK];
  __shared__ __align__(16) u16 Ks2[32 * LDK];
  __shared__ __align__(16) u16 Vs[128 * LDV];
  __shared__ __align__(16) u16 Ps[4 * 2 * 16 * LDP];
  const float scale = 0.08838834764831845f;  // 1/sqrt(128)
  int h = blockIdx.y, qt = blockIdx.x;
  size_t hoff = (size_t)h * S_LEN * DH;
  const u16* q1 = q1g + hoff;
  const u16* q2 = q2g + hoff;
  const u16* k1 = k1g + hoff;
  const u16* k2 = k2g + hoff;
  const u16* vt = vtg + hoff;
  int t = threadIdx.x, wid = t >> 6, lane = t & 63;
  int fr = lane & 15, fq = lane >> 4;
  int qrow = qt * 64 + wid * 16 + fr;
  bf16x8 qf1[4], qf2[4];
#pragma unroll
  for (int ks = 0; ks < 4; ks++) {
    qf1[ks] = *(const bf16x8*)&q1[(size_t)qrow * DH + ks * 32 + fq * 8];
    qf2[ks] = *(const bf16x8*)&q2[(size_t)qrow * DH + ks * 32 + fq * 8];
  }
  bf16x8 ones;
#pragma unroll
  for (int i = 0; i < 8; i++) ones[i] = (__bf16)1.0f;

  f32x4 O1[8] = {};
  f32x4 O2[8] = {};
  f32x4 L1 = {};
  f32x4 L2 = {};
  int skr = t >> 3, skc = (t & 7) << 4;
  int svr = t >> 2, svc = (t & 3) << 3;
  u16* myP1 = &Ps[(wid * 2 + 0) * 16 * LDP];
  u16* myP2 = &Ps[(wid * 2 + 1) * 16 * LDP];

  for (int kt = 0; kt < S_LEN; kt += 32) {
    uint4 ka1 = *(const uint4*)&k1[(size_t)(kt + skr) * DH + skc];
    uint4 kb1 = *(const uint4*)&k1[(size_t)(kt + skr) * DH + skc + 8];
    uint4 ka2 = *(const uint4*)&k2[(size_t)(kt + skr) * DH + skc];
    uint4 kb2 = *(const uint4*)&k2[(size_t)(kt + skr) * DH + skc + 8];
    uint4 va = *(const uint4*)&vt[(size_t)svr * S_LEN + kt + svc];
    uint4 vb = *(const uint4*)&vt[(size_t)(svr + 64) * S_LEN + kt + svc];
    __syncthreads();
    *(uint4*)&Ks1[skr * LDK + skc] = ka1;
    *(uint4*)&Ks1[skr * LDK + skc + 8] = kb1;
    *(uint4*)&Ks2[skr * LDK + skc] = ka2;
    *(uint4*)&Ks2[skr * LDK + skc + 8] = kb2;
    *(uint4*)&Vs[svr * LDV + svc] = va;
    *(uint4*)&Vs[(svr + 64) * LDV + svc] = vb;
    __syncthreads();

    f32x4 s1[2] = {};
    f32x4 s2[2] = {};
#pragma unroll
    for (int nf = 0; nf < 2; nf++)
#pragma unroll
      for (int ks = 0; ks < 4; ks++) {
        bf16x8 b1v = *(const bf16x8*)&Ks1[(nf * 16 + fr) * LDK + ks * 32 + fq * 8];
        s1[nf] = __builtin_amdgcn_mfma_f32_16x16x32_bf16(qf1[ks], b1v, s1[nf], 0, 0, 0);
        bf16x8 b2v = *(const bf16x8*)&Ks2[(nf * 16 + fr) * LDK + ks * 32 + fq * 8];
        s2[nf] = __builtin_amdgcn_mfma_f32_16x16x32_bf16(qf2[ks], b2v, s2[nf], 0, 0, 0);
      }

    // static softmax: p = exp(s*scale); no max subtraction, no rescale
#pragma unroll
    for (int nf = 0; nf < 2; nf++)
#pragma unroll
      for (int r = 0; r < 4; r++) {
        myP1[(fq * 4 + r) * LDP + nf * 16 + fr] = f2bf(__expf(s1[nf][r] * scale));
        myP2[(fq * 4 + r) * LDP + nf * 16 + fr] = f2bf(__expf(s2[nf][r] * scale));
      }
    asm volatile("s_waitcnt lgkmcnt(0)" ::: "memory");
    bf16x8 pa1 = *(const bf16x8*)&myP1[fr * LDP + fq * 8];
    bf16x8 pa2 = *(const bf16x8*)&myP2[fr * LDP + fq * 8];
    L1 = __builtin_amdgcn_mfma_f32_16x16x32_bf16(pa1, ones, L1, 0, 0, 0);
    L2 = __builtin_amdgcn_mfma_f32_16x16x32_bf16(pa2, ones, L2, 0, 0, 0);
#pragma unroll
    for (int f = 0; f < 8; f++) {
      bf16x8 bv = *(const bf16x8*)&Vs[(f * 16 + fr) * LDV + fq * 8];
      O1[f] = __builtin_amdgcn_mfma_f32_16x16x32_bf16(pa1, bv, O1[f], 0, 0, 0);
      O2[f] = __builtin_amdgcn_mfma_f32_16x16x32_bf16(pa2, bv, O2[f], 0, 0, 0);
    }
  }

  float lam = lamw[h];
#pragma unroll
  for (int r = 0; r < 4; r++) {
    float i1 = 1.0f / L1[r], i2 = lam / L2[r];
#pragma unroll
    for (int f = 0; f < 8; f++) {
      float val = O1[f][r] * i1 - O2[f][r] * i2;
      og[(size_t)(qt * 64 + wid * 16 + fq * 4 + r) * (NH * DH) + h * DH + f * 16 + fr] =
          f2bf(val);
    }
  }
}

// ---------------------------------------------------------------------------
extern "C" void kernel_launch(void* const* d_in, const int* in_sizes, int n_in,
                              void* d_out, int out_size, void* d_ws, size_t ws_size,
                              hipStream_t stream) {
  const float* x = (const float*)d_in[0];
  const float* g = (const float*)d_in[1];
  const float* Wq1 = (const float*)d_in[2];
  const float* Wq2 = (const float*)d_in[3];
  const float* Wk1 = (const float*)d_in[4];
  const float* Wk2 = (const float*)d_in[5];
  const float* Wv = (const float*)d_in[6];
  const float* lq1 = (const float*)d_in[7];
  const float* lk1 = (const float*)d_in[8];
  const float* lq2 = (const float*)d_in[9];
  const float* lk2 = (const float*)d_in[10];
  const float* Wo = (const float*)d_in[11];
  const float* W1 = (const float*)d_in[12];
  const float* W2 = (const float*)d_in[13];
  const float* W3 = (const float*)d_in[14];

  char* ws = (char*)d_ws;
  size_t off = 0;
  auto alloc = [&](size_t b) {
    char* p = ws + off;
    off += (b + 255) & ~(size_t)255;
    return p;
  };
  const size_t PROJ_B = (size_t)NH * DH * D_DIM * 2;  // 8.39 MB, 256-aligned
  // 5 proj weights contiguous -> one flattened N=10240 GEMM reads them as Wcat
  u16* wq1t = (u16*)alloc(PROJ_B);
  u16* wq2t = (u16*)alloc(PROJ_B);
  u16* wk1t = (u16*)alloc(PROJ_B);
  u16* wk2t = (u16*)alloc(PROJ_B);
  u16* wvt = (u16*)alloc(PROJ_B);
  u16* wot = (u16*)alloc((size_t)D_DIM * NH * DH * 2);
  u16* w1t = (u16*)alloc((size_t)HID * D_DIM * 2);
  u16* w2t = (u16*)alloc((size_t)HID * D_DIM * 2);
  u16* w3t = (u16*)alloc((size_t)D_DIM * HID * 2);
  u16* xnb = (u16*)alloc((size_t)S_LEN * D_DIM * 2);
  float* xnf = (float*)alloc((size_t)S_LEN * D_DIM * 4);
  // 5 proj outputs contiguous (q1,q2,k1,k2,v); q1b..k2b region (33.5 MB) is
  // dead after flash_attn and reused as the W3 split-K partial buffer.
  u16* q1b = (u16*)alloc(PROJ_B);
  u16* q2b = (u16*)alloc(PROJ_B);
  u16* k1b = (u16*)alloc(PROJ_B);
  u16* k2b = (u16*)alloc(PROJ_B);
  u16* vb = (u16*)alloc(PROJ_B);
  u16* vtb = (u16*)alloc(PROJ_B);
  float* lamw = (float*)alloc(NH * 4);
  u16* oa = (u16*)alloc((size_t)S_LEN * NH * DH * 2);
  float* hf = (float*)alloc((size_t)S_LEN * D_DIM * 4);
  u16* zb = (u16*)alloc((size_t)S_LEN * D_DIM * 2);
  u16* ffb = (u16*)alloc((size_t)S_LEN * HID * 2);
  (void)q2b; (void)k2b;
  if (off > ws_size) return;  // workspace too small: out stays zero -> loud failure

  dim3 tpb(32, 8);
  // weight transposes (fp32 -> bf16, [K,N] -> [N,K])
  tconv_f2b<<<dim3(DH / 32, D_DIM / 32, NH), tpb, 0, stream>>>(Wq1, wq1t, D_DIM, DH);
  tconv_f2b<<<dim3(DH / 32, D_DIM / 32, NH), tpb, 0, stream>>>(Wq2, wq2t, D_DIM, DH);
  tconv_f2b<<<dim3(DH / 32, D_DIM / 32, NH), tpb, 0, stream>>>(Wk1, wk1t, D_DIM, DH);
  tconv_f2b<<<dim3(DH / 32, D_DIM / 32, NH), tpb, 0, stream>>>(Wk2, wk2t, D_DIM, DH);
  tconv_f2b<<<dim3(DH / 32, D_DIM / 32, NH), tpb, 0, stream>>>(Wv, wvt, D_DIM, DH);
  tconv_f2b<<<dim3(D_DIM / 32, (NH * DH) / 32, 1), tpb, 0, stream>>>(Wo, wot, NH * DH, D_DIM);
  tconv_f2b<<<dim3(HID / 32, D_DIM / 32, 1), tpb, 0, stream>>>(W1, w1t, D_DIM, HID);
  tconv_f2b<<<dim3(HID / 32, D_DIM / 32, 1), tpb, 0, stream>>>(W2, w2t, D_DIM, HID);
  tconv_f2b<<<dim3(D_DIM / 32, HID / 32, 1), tpb, 0, stream>>>(W3, w3t, HID, D_DIM);

  rmsnorm_kernel<<<S_LEN, 256, 0, stream>>>(x, g, xnf, xnb);
  lam_kernel<<<1, 256, 0, stream>>>(lq1, lk1, lq2, lk2, lamw);

  // all 5 projections as ONE flattened GEMM: N = 5*16*128 = 10240
  gemm9<0><<<dim3((5 * NH * DH) / 128, S_LEN / 128), 256, 0, stream>>>(
      xnb, wq1t, nullptr, q1b, nullptr, 5 * NH * DH, D_DIM, D_DIM);
  // V -> V^T per head
  tconv_b2b<<<dim3(DH / 32, S_LEN / 32, NH), tpb, 0, stream>>>(vb, vtb, S_LEN, DH);

  flash_attn<<<dim3(S_LEN / 64, NH), 256, 0, stream>>>(q1b, q2b, k1b, k2b, vtb, lamw, oa);

  // h = o @ Wo + xn  (fp32)
  gemm9<1><<<dim3(D_DIM / 128, S_LEN / 128), 256, 0, stream>>>(
      oa, wot, nullptr, hf, xnf, D_DIM, NH * DH, NH * DH);
  // z = rmsnorm(h)
  rmsnorm_kernel<<<S_LEN, 256, 0, stream>>>(hf, g, nullptr, zb);
  // gate = silu(z@W1) * (z@W2)  (bf16), dual-B
  gemm9<2><<<dim3(HID / 128, S_LEN / 128), 256, 0, stream>>>(
      zb, w1t, w2t, ffb, nullptr, HID, D_DIM, D_DIM);
  // out = gate @ W3 + h: split-K=2 (2 blocks/CU instead of 1) -> fp32
  // partials in dead q1b region, then combine adds residual.
  float* Pw3 = (float*)q1b;
  gemm9<3><<<dim3(D_DIM / 128, S_LEN / 128, 2), 256, 0, stream>>>(
      ffb, w3t, nullptr, Pw3, nullptr, D_DIM, HID / 2, HID);
  combine2<<<(S_LEN * D_DIM / 4 + 255) / 256, 256, 0, stream>>>(
      Pw3, hf, (float*)d_out, S_LEN * D_DIM / 4);
}